// Round 9
// baseline (697.639 us; speedup 1.0000x reference)
//
#include <hip/hip_runtime.h>
#include <hip/hip_bf16.h>

#define BATCH 2
#define SEQ 2048
#define DM 1024
#define NH 16
#define DH 64
#define MTOT (BATCH*SEQ)

typedef __attribute__((ext_vector_type(8))) short bf16x8;
typedef __attribute__((ext_vector_type(4))) float f32x4;
typedef __attribute__((ext_vector_type(16))) float f32x16;
typedef __attribute__((ext_vector_type(4))) float float4v;
typedef __attribute__((ext_vector_type(8))) unsigned short u16x8;
typedef __attribute__((ext_vector_type(4))) unsigned short u16x4;

#define GLDS16(g, l) __builtin_amdgcn_global_load_lds(                         \
    (const __attribute__((address_space(1))) void*)(g),                        \
    (__attribute__((address_space(3))) void*)(l), 16, 0, 0)

static __device__ __forceinline__ float bf2f(unsigned short u) {
    unsigned int x = ((unsigned int)u) << 16;
    float f; __builtin_memcpy(&f, &x, 4); return f;
}
static __device__ __forceinline__ unsigned short f2bf(float f) {
    unsigned int x; __builtin_memcpy(&x, &f, 4);
    x += 0x7fffu + ((x >> 16) & 1);   // RNE
    return (unsigned short)(x >> 16);
}
static __device__ __forceinline__ unsigned int cvt_pk_bf16(float a, float b) {
    unsigned int r;
    asm volatile("v_cvt_pk_bf16_f32 %0, %1, %2" : "=v"(r) : "v"(a), "v"(b));
    return r;
}

// ---------------- prep: fused {q,k,v fp32->bf16} + {W^T fp32->bf16} ----------------
__global__ __launch_bounds__(256) void prep_kernel(
    const float* __restrict__ q, const float* __restrict__ k, const float* __restrict__ v,
    unsigned short* __restrict__ oq, unsigned short* __restrict__ ok_, unsigned short* __restrict__ ov,
    const float* __restrict__ w0, const float* __restrict__ w1,
    const float* __restrict__ w2, const float* __restrict__ w3,
    unsigned short* __restrict__ t0, unsigned short* __restrict__ t1,
    unsigned short* __restrict__ t2, unsigned short* __restrict__ t3) {
    __shared__ float tile[64][65];
    const int bx = blockIdx.x, t = threadIdx.x;
    if (bx < 6144) {              // cvt part: 3 slabs x 2048 blocks
        const int slab = bx >> 11, bxr = bx & 2047;
        const float* in = slab == 0 ? q : (slab == 1 ? k : v);
        unsigned short* out = slab == 0 ? oq : (slab == 1 ? ok_ : ov);
        size_t i = ((size_t)bxr * 256 + t) * 8;
        float4v a = *(const float4v*)(in + i);
        float4v b = *(const float4v*)(in + i + 4);
        u16x8 r;
        r[0]=f2bf(a[0]); r[1]=f2bf(a[1]); r[2]=f2bf(a[2]); r[3]=f2bf(a[3]);
        r[4]=f2bf(b[0]); r[5]=f2bf(b[1]); r[6]=f2bf(b[2]); r[7]=f2bf(b[3]);
        *(u16x8*)(out + i) = r;
    } else {                      // wtrans part: 4 weights x 256 tiles
        const int i2 = bx - 6144;
        const int z = i2 >> 8, rem = i2 & 255;
        const float* w = z==0 ? w0 : z==1 ? w1 : z==2 ? w2 : w3;
        unsigned short* wt = z==0 ? t0 : z==1 ? t1 : z==2 ? t2 : t3;
        const int k0 = (rem & 15) * 64, n0 = (rem >> 4) * 64;
        const int tr = t >> 4, tc = t & 15;
#pragma unroll
        for (int i = 0; i < 4; ++i) {
            float4v val = *(const float4v*)(w + (size_t)(k0 + tr + 16*i) * DM + n0 + tc*4);
            tile[tr + 16*i][tc*4 + 0] = val[0];
            tile[tr + 16*i][tc*4 + 1] = val[1];
            tile[tr + 16*i][tc*4 + 2] = val[2];
            tile[tr + 16*i][tc*4 + 3] = val[3];
        }
        __syncthreads();
#pragma unroll
        for (int i = 0; i < 4; ++i) {
            u16x4 o;
#pragma unroll
            for (int j = 0; j < 4; ++j) o[j] = f2bf(tile[tc*4 + j][tr + 16*i]);
            *(u16x4*)(wt + (size_t)(n0 + tr + 16*i) * DM + k0 + tc*4) = o;
        }
    }
}

// ---------------- GEMM body: BM=128, BN=64; OUTMODE 0 bf16, 1 f32, 2 per-head-V^T ----------------
template<int OUTMODE>
static __device__ __forceinline__ void gemm_body(
    const unsigned short* __restrict__ A, const unsigned short* __restrict__ Bt,
    const float* __restrict__ bias, void* __restrict__ Cout,
    unsigned short* a_lds, unsigned short* b_lds) {
    constexpr int BM = 128, BN = 64, BK = 64, NT = DM / BK;
    const int tid = threadIdx.x;
    const int m0 = blockIdx.y * BM, n0 = blockIdx.x * BN;
    const int w = tid >> 6, l = tid & 63;
    const int lr = l & 15, lg = l >> 4;
    const int wm = (w >> 1) * 64, wn = (w & 1) * 32;
    f32x4 acc[4][2] = {};

    auto stage = [&](int buf, int kt) {
        const int k0 = kt * BK;
#pragma unroll
        for (int i = 0; i < 4; ++i) {
            int u = i*256 + tid;
            int row = u >> 3, slot = u & 7;
            int sc = (slot ^ (row & 7)) * 8;
            GLDS16(A + (size_t)(m0 + row)*DM + k0 + sc, a_lds + buf*BM*BK + u*8);
        }
#pragma unroll
        for (int i = 0; i < 2; ++i) {
            int u = i*256 + tid;
            int row = u >> 3, slot = u & 7;
            int sc = (slot ^ (row & 7)) * 8;
            GLDS16(Bt + (size_t)(n0 + row)*DM + k0 + sc, b_lds + buf*BN*BK + u*8);
        }
    };

    stage(0, 0);
    for (int kt = 0; kt < NT; ++kt) {
        __syncthreads();
        if (kt < NT-1) stage((kt+1)&1, kt+1);
        const char* ab = (const char*)(a_lds + (kt&1)*BM*BK);
        const char* bb = (const char*)(b_lds + (kt&1)*BN*BK);
        bf16x8 af[4][2], bfr[2][2];
#pragma unroll
        for (int r = 0; r < 4; ++r)
#pragma unroll
            for (int kc = 0; kc < 2; ++kc) {
                int row = wm + r*16 + lr;
                af[r][kc] = *(const bf16x8*)(ab + row*128 + ((kc*64 + lg*16) ^ ((row&7)<<4)));
            }
#pragma unroll
        for (int c = 0; c < 2; ++c)
#pragma unroll
            for (int kc = 0; kc < 2; ++kc) {
                int row = wn + c*16 + lr;
                bfr[c][kc] = *(const bf16x8*)(bb + row*128 + ((kc*64 + lg*16) ^ ((row&7)<<4)));
            }
#pragma unroll
        for (int r = 0; r < 4; ++r)
#pragma unroll
            for (int c = 0; c < 2; ++c)
#pragma unroll
                for (int kc = 0; kc < 2; ++kc)
                    acc[r][c] = __builtin_amdgcn_mfma_f32_16x16x32_bf16(af[r][kc], bfr[c][kc], acc[r][c], 0, 0, 0);
    }

#pragma unroll
    for (int r = 0; r < 4; ++r)
#pragma unroll
        for (int c = 0; c < 2; ++c) {
            int m = m0 + wm + r*16 + lg*4;
            int n = n0 + wn + c*16 + lr;
            float bb = bias[n];
            if constexpr (OUTMODE == 1) {
                float* o = (float*)Cout;
#pragma unroll
                for (int j = 0; j < 4; ++j) o[(size_t)(m+j)*DM + n] = acc[r][c][j] + bb;
            } else if constexpr (OUTMODE == 0) {
                unsigned short* o = (unsigned short*)Cout;
#pragma unroll
                for (int j = 0; j < 4; ++j) o[(size_t)(m+j)*DM + n] = f2bf(acc[r][c][j] + bb);
            } else {
                // per-head V^T: vtg[(b*16 + n/64)*64 + n%64][k], k = m % SEQ (4 contiguous)
                unsigned short* o = (unsigned short*)Cout;
                int bb_ = m >> 11, kk = m & (SEQ-1);
                int bh = bb_ * NH + (n >> 6), d = n & 63;
                u16x4 ov;
#pragma unroll
                for (int j = 0; j < 4; ++j) ov[j] = f2bf(acc[r][c][j] + bb);
                *(u16x4*)(o + ((size_t)bh*DH + d)*SEQ + kk) = ov;
            }
        }
}

__global__ __launch_bounds__(256, 3) void gemm_qkv_kernel(
    const unsigned short* __restrict__ A0, const unsigned short* __restrict__ A1, const unsigned short* __restrict__ A2,
    const unsigned short* __restrict__ B0, const unsigned short* __restrict__ B1, const unsigned short* __restrict__ B2,
    const float* __restrict__ c0, const float* __restrict__ c1, const float* __restrict__ c2,
    unsigned short* __restrict__ O0, unsigned short* __restrict__ O1, unsigned short* __restrict__ O2) {
    __shared__ __align__(16) unsigned short smem[2*128*64 + 2*64*64];   // 48 KB
    const int z = blockIdx.z;
    const unsigned short* A = z==0 ? A0 : z==1 ? A1 : A2;
    const unsigned short* B = z==0 ? B0 : z==1 ? B1 : B2;
    const float* c = z==0 ? c0 : z==1 ? c1 : c2;
    unsigned short* O = z==0 ? O0 : z==1 ? O1 : O2;
    if (z == 2) gemm_body<2>(A, B, c, O, smem, smem + 2*128*64);
    else        gemm_body<0>(A, B, c, O, smem, smem + 2*128*64);
}

__global__ __launch_bounds__(256, 3) void gemm_out_kernel(
    const unsigned short* __restrict__ A, const unsigned short* __restrict__ Bt,
    const float* __restrict__ bias, float* __restrict__ Cout) {
    __shared__ __align__(16) unsigned short smem[2*128*64 + 2*64*64];   // 48 KB
    gemm_body<1>(A, Bt, bias, Cout, smem, smem + 2*128*64);
}

// ---------------- attn_den: softmax denominators only (no V, no oacc) ----------------
// 8 waves: waves 0-3 q-slabs x keys 0..1023, waves 4-7 same slabs x keys 1024..2047.
__global__ __launch_bounds__(512, 6) void attn_den_kernel(
    const unsigned short* __restrict__ qw, const unsigned short* __restrict__ kw,
    const float* __restrict__ mask, float* __restrict__ rinv_out) {
    constexpr int QB = 128, KB = 64, NT2 = SEQ / KB / 2;
    __shared__ __align__(16) unsigned short smem[4*KB*DH + 4096];   // 32 KB K dbuf + 8 KB mask
    unsigned short* kbuf = smem;
    float* madd_f = (float*)(smem + 4*KB*DH);
    const int tid = threadIdx.x, w = tid >> 6, l = tid & 63;
    const int hh = w >> 2, ws = w & 3;
    const int q32 = l & 31, hi = l >> 5;
    const int u0 = (blockIdx.x & 7) * 64 + (blockIdx.x >> 3);
    const int qblk = u0 & 15, bh = u0 >> 4;
    const int b = bh >> 4, h = bh & 15;
    const int q0 = qblk * QB;
    const int q = q0 + ws*32 + q32;
    const int kbase = hh * (SEQ/2);

    {
        int idx = tid * 4;
        float4v m4 = *(const float4v*)(mask + (size_t)b*SEQ + idx);
        float4v md;
#pragma unroll
        for (int r = 0; r < 4; ++r) md[r] = (1.0f - m4[r]) * (-1e9f);
        *(float4v*)(madd_f + idx) = md;
    }

    bf16x8 qf[4];
    {
        const unsigned short* qp = qw + ((size_t)(b*SEQ + q))*DM + h*DH + hi*8;
#pragma unroll
        for (int ks = 0; ks < 4; ++ks) {
            bf16x8 t = *(const bf16x8*)(qp + ks*16);
#pragma unroll
            for (int j = 0; j < 8; ++j) t[j] = (short)f2bf(bf2f((unsigned short)t[j]) * 0.125f);
            qf[ks] = t;
        }
    }

    auto stageK = [&](int buf, int kt) {
#pragma unroll
        for (int hf = 0; hf < 2; ++hf) {
            int row = tid >> 3, slot = tid & 7;
            int sc = (slot ^ (row & 7)) * 8;
            const unsigned short* base = kw + ((size_t)(b*SEQ + hf*(SEQ/2) + kt*KB + row))*DM + h*DH;
            GLDS16(base + sc, kbuf + (buf*2 + hf)*KB*DH + tid*8);
        }
    };

    float rs = 0.f;
    stageK(0, 0);
    for (int kt = 0; kt < NT2; ++kt) {
        __syncthreads();
        if (kt < NT2-1) stageK((kt+1)&1, kt+1);
        const char* kb = (const char*)(kbuf + ((kt&1)*2 + hh)*KB*DH);
#pragma unroll
        for (int sub = 0; sub < 2; ++sub) {
            f32x16 s = {};
#pragma unroll
            for (int ks = 0; ks < 4; ++ks) {
                int key = sub*32 + q32;
                bf16x8 kf = *(const bf16x8*)(kb + key*128 + ((ks*32 + hi*16) ^ ((key&7)<<4)));
                s = __builtin_amdgcn_mfma_f32_32x32x16_bf16(kf, qf[ks], s, 0, 0, 0);
            }
#pragma unroll
            for (int rq = 0; rq < 4; ++rq) {
                float4v m4 = *(const float4v*)(madd_f + kbase + kt*KB + sub*32 + rq*8 + hi*4);
#pragma unroll
                for (int r = 0; r < 4; ++r)
                    rs += __expf(s[rq*4 + r] + m4[r]);
            }
        }
    }
    rs += __shfl_xor(rs, 32);
    // combine key-half partials via LDS, then write 1/rs
    float* rbuf = (float*)smem;
    __syncthreads();
    rbuf[w*64 + l] = rs;
    __syncthreads();
    rs += rbuf[(w ^ 4)*64 + l];
    if (hh == 0 && l < 32)
        rinv_out[(size_t)bh*SEQ + q] = 1.0f / rs;
}

// ---------------- attn_out: probabilities (non-temporal) + PV ----------------
__global__ __launch_bounds__(512, 4) void attn_out_kernel(
    const unsigned short* __restrict__ qw, const unsigned short* __restrict__ kw,
    const unsigned short* __restrict__ vtg, const float* __restrict__ mask,
    const float* __restrict__ rinv_g, float* __restrict__ attn_out,
    unsigned short* __restrict__ ctx) {
    constexpr int QB = 128, KB = 64, NT2 = SEQ / KB / 2;
    __shared__ __align__(16) unsigned short smem[4*KB*DH + 4*KB*DH + 4096];  // 72 KB
    unsigned short* kbuf = smem;
    unsigned short* vbuf = smem + 4*KB*DH;
    float* madd_f = (float*)(smem + 8*KB*DH);
    const int tid = threadIdx.x, w = tid >> 6, l = tid & 63;
    const int hh = w >> 2, ws = w & 3;
    const int q32 = l & 31, hi = l >> 5;
    const int u0 = (blockIdx.x & 7) * 64 + (blockIdx.x >> 3);
    const int qblk = u0 & 15, bh = u0 >> 4;
    const int b = bh >> 4, h = bh & 15;
    const int q0 = qblk * QB;
    const int q = q0 + ws*32 + q32;
    const int kbase = hh * (SEQ/2);

    {
        int idx = tid * 4;
        float4v m4 = *(const float4v*)(mask + (size_t)b*SEQ + idx);
        float4v md;
#pragma unroll
        for (int r = 0; r < 4; ++r) md[r] = (1.0f - m4[r]) * (-1e9f);
        *(float4v*)(madd_f + idx) = md;
    }
    const float rinv = rinv_g[(size_t)bh*SEQ + q];

    bf16x8 qf[4];
    {
        const unsigned short* qp = qw + ((size_t)(b*SEQ + q))*DM + h*DH + hi*8;
#pragma unroll
        for (int ks = 0; ks < 4; ++ks) {
            bf16x8 t = *(const bf16x8*)(qp + ks*16);
#pragma unroll
            for (int j = 0; j < 8; ++j) t[j] = (short)f2bf(bf2f((unsigned short)t[j]) * 0.125f);
            qf[ks] = t;
        }
    }

    auto stageK = [&](int buf, int kt) {
#pragma unroll
        for (int hf = 0; hf < 2; ++hf) {
            int row = tid >> 3, slot = tid & 7;
            int sc = (slot ^ (row & 7)) * 8;
            const unsigned short* base = kw + ((size_t)(b*SEQ + hf*(SEQ/2) + kt*KB + row))*DM + h*DH;
            GLDS16(base + sc, kbuf + (buf*2 + hf)*KB*DH + tid*8);
        }
    };
    auto stageV = [&](int buf, int kt) {
#pragma unroll
        for (int hf = 0; hf < 2; ++hf) {
            int row = tid >> 3, slot = tid & 7;
            int sc = (slot ^ (row & 7)) * 8;
            const unsigned short* base = vtg + ((size_t)bh*DH + row)*SEQ + hf*(SEQ/2) + kt*KB;
            GLDS16(base + sc, vbuf + (buf*2 + hf)*KB*DH + tid*8);
        }
    };

    f32x16 oacc[2] = {};
    float* attn_row = attn_out + ((size_t)bh*SEQ + q)*SEQ + kbase;
    stageK(0, 0); stageV(0, 0);
    for (int kt = 0; kt < NT2; ++kt) {
        __syncthreads();
        if (kt < NT2-1) { stageK((kt+1)&1, kt+1); stageV((kt+1)&1, kt+1); }
        const char* kb = (const char*)(kbuf + ((kt&1)*2 + hh)*KB*DH);
        const char* vb = (const char*)(vbuf + ((kt&1)*2 + hh)*KB*DH);
#pragma unroll
        for (int sub = 0; sub < 2; ++sub) {
            f32x16 s = {};
#pragma unroll
            for (int ks = 0; ks < 4; ++ks) {
                int key = sub*32 + q32;
                bf16x8 kf = *(const bf16x8*)(kb + key*128 + ((ks*32 + hi*16) ^ ((key&7)<<4)));
                s = __builtin_amdgcn_mfma_f32_32x32x16_bf16(kf, qf[ks], s, 0, 0, 0);
            }
#pragma unroll
            for (int half = 0; half < 2; ++half) {
                float4v pv0, pv1;
                {
                    const int rq = half*2;
                    float4v m4 = *(const float4v*)(madd_f + kbase + kt*KB + sub*32 + rq*8 + hi*4);
#pragma unroll
                    for (int r = 0; r < 4; ++r) pv0[r] = __expf(s[rq*4 + r] + m4[r]) * rinv;
                    __builtin_nontemporal_store(pv0, (float4v*)(attn_row + kt*KB + sub*32 + rq*8 + hi*4));
                }
                {
                    const int rq = half*2 + 1;
                    float4v m4 = *(const float4v*)(madd_f + kbase + kt*KB + sub*32 + rq*8 + hi*4);
#pragma unroll
                    for (int r = 0; r < 4; ++r) pv1[r] = __expf(s[rq*4 + r] + m4[r]) * rinv;
                    __builtin_nontemporal_store(pv1, (float4v*)(attn_row + kt*KB + sub*32 + rq*8 + hi*4));
                }
                unsigned int w0 = cvt_pk_bf16(pv0[0], pv0[1]);
                unsigned int w1 = cvt_pk_bf16(pv0[2], pv0[3]);
                unsigned int w2 = cvt_pk_bf16(pv1[0], pv1[1]);
                unsigned int w3 = cvt_pk_bf16(pv1[2], pv1[3]);
                asm volatile("v_permlane32_swap_b32 %0, %1" : "+v"(w0), "+v"(w2));
                asm volatile("v_permlane32_swap_b32 %0, %1" : "+v"(w1), "+v"(w3));
                union { unsigned int uu[4]; bf16x8 v; } pa;
                pa.uu[0] = w0; pa.uu[1] = w1; pa.uu[2] = w2; pa.uu[3] = w3;
                const int ks4 = sub*2 + half;
#pragma unroll
                for (int dsub = 0; dsub < 2; ++dsub) {
                    int d = dsub*32 + q32;
                    bf16x8 vf = *(const bf16x8*)(vb + d*128 + ((ks4*32 + hi*16) ^ ((d&7)<<4)));
                    oacc[dsub] = __builtin_amdgcn_mfma_f32_32x32x16_bf16(pa.v, vf, oacc[dsub], 0, 0, 0);
                }
            }
        }
    }

    // combine ctx partials across key-half wave pairs (stride 36 dodges bank conflicts)
    float* cbuf = (float*)smem;
    __syncthreads();
    if (w >= 4) {
        int base = ((w - 4)*64 + l) * 36;
        *(f32x16*)(cbuf + base) = oacc[0];
        *(f32x16*)(cbuf + base + 16) = oacc[1];
    }
    __syncthreads();
    if (w < 4) {
        int base = (w*64 + l) * 36;
        oacc[0] += *(const f32x16*)(cbuf + base);
        oacc[1] += *(const f32x16*)(cbuf + base + 16);
#pragma unroll
        for (int dsub = 0; dsub < 2; ++dsub) {
            int d = h*DH + dsub*32 + q32;
#pragma unroll
            for (int reg = 0; reg < 16; ++reg) {
                int qr = q0 + ws*32 + (reg&3) + 8*(reg>>2) + 4*hi;
                ctx[(size_t)(b*SEQ + qr)*DM + d] = f2bf(oacc[dsub][reg]);
            }
        }
    }
}

extern "C" void kernel_launch(void* const* d_in, const int* in_sizes, int n_in,
                              void* d_out, int out_size, void* d_ws, size_t ws_size,
                              hipStream_t stream) {
    const float* query = (const float*)d_in[0];
    const float* key_  = (const float*)d_in[1];
    const float* value = (const float*)d_in[2];
    const float* mask  = (const float*)d_in[3];
    const float* W_q = (const float*)d_in[4];
    const float* b_q = (const float*)d_in[5];
    const float* W_k = (const float*)d_in[6];
    const float* b_k = (const float*)d_in[7];
    const float* W_v = (const float*)d_in[8];
    const float* b_v = (const float*)d_in[9];
    const float* W_o = (const float*)d_in[10];
    const float* b_o = (const float*)d_in[11];

    char* ws = (char*)d_ws;
    const size_t SZ = (size_t)MTOT * DM * 2;          // 8 MiB per bf16 [4096][1024]
    unsigned short* xq  = (unsigned short*)(ws);
    unsigned short* xk  = (unsigned short*)(ws + SZ);
    unsigned short* xv  = (unsigned short*)(ws + 2*SZ);
    unsigned short* wtq = (unsigned short*)(ws + 3*SZ);
    unsigned short* wtk = wtq + (size_t)DM*DM;
    unsigned short* wtv = wtk + (size_t)DM*DM;
    unsigned short* wto = wtv + (size_t)DM*DM;
    unsigned short* qws = (unsigned short*)(ws + 4*SZ);
    unsigned short* kws = (unsigned short*)(ws + 5*SZ);
    unsigned short* vtg = (unsigned short*)(ws + 6*SZ);  // per-head V^T from gemm_qkv z=2
    unsigned short* ctx = (unsigned short*)(ws + 7*SZ);
    float* rinv = (float*)(ws + 8*SZ);                   // [32][2048] = 256 KB
    float* out_f  = (float*)d_out;
    float* attn_f = out_f + (size_t)MTOT * DM;

    prep_kernel<<<dim3(7168), 256, 0, stream>>>(query, key_, value, xq, xk, xv,
                                                W_q, W_k, W_v, W_o, wtq, wtk, wtv, wto);
    gemm_qkv_kernel<<<dim3(16, 32, 3), 256, 0, stream>>>(xq, xk, xv, wtq, wtk, wtv,
                                                         b_q, b_k, b_v, qws, kws, vtg);
    attn_den_kernel<<<dim3(512), 512, 0, stream>>>(qws, kws, mask, rinv);
    attn_out_kernel<<<dim3(512), 512, 0, stream>>>(qws, kws, vtg, mask, rinv, attn_f, ctx);
    gemm_out_kernel<<<dim3(16, 32), 256, 0, stream>>>(ctx, wto, b_o, out_f);
}

// Round 11
// 277.563 us; speedup vs baseline: 2.5134x; 2.5134x over previous
//
#include <hip/hip_runtime.h>
#include <hip/hip_bf16.h>

#define BATCH 2
#define SEQ 2048
#define DM 1024
#define NH 16
#define DH 64
#define MTOT (BATCH*SEQ)

typedef __attribute__((ext_vector_type(8))) short bf16x8;
typedef __attribute__((ext_vector_type(4))) float f32x4;
typedef __attribute__((ext_vector_type(16))) float f32x16;
typedef __attribute__((ext_vector_type(4))) float float4v;
typedef __attribute__((ext_vector_type(8))) unsigned short u16x8;
typedef __attribute__((ext_vector_type(4))) unsigned short u16x4;

#define GLDS16(g, l) __builtin_amdgcn_global_load_lds(                         \
    (const __attribute__((address_space(1))) void*)(g),                        \
    (__attribute__((address_space(3))) void*)(l), 16, 0, 0)

static __device__ __forceinline__ float bf2f(unsigned short u) {
    unsigned int x = ((unsigned int)u) << 16;
    float f; __builtin_memcpy(&f, &x, 4); return f;
}
static __device__ __forceinline__ unsigned short f2bf(float f) {
    unsigned int x; __builtin_memcpy(&x, &f, 4);
    x += 0x7fffu + ((x >> 16) & 1);   // RNE
    return (unsigned short)(x >> 16);
}
static __device__ __forceinline__ unsigned int cvt_pk_bf16(float a, float b) {
    unsigned int r;
    asm volatile("v_cvt_pk_bf16_f32 %0, %1, %2" : "=v"(r) : "v"(a), "v"(b));
    return r;
}
// Cross-lane same-wave LDS handoff fence: compiler wave fence + drain LDS queue.
// Plain HIP has NO dependence edge for lane A ds_write -> lane B ds_read (R10 bug).
static __device__ __forceinline__ void lds_fence() {
    __builtin_amdgcn_wave_barrier();
    asm volatile("s_waitcnt lgkmcnt(0)" ::: "memory");
    __builtin_amdgcn_sched_barrier(0);
}

// ---------------- prep: fused {q,k,v fp32->bf16} + {W^T fp32->bf16} ----------------
__global__ __launch_bounds__(256) void prep_kernel(
    const float* __restrict__ q, const float* __restrict__ k, const float* __restrict__ v,
    unsigned short* __restrict__ oq, unsigned short* __restrict__ ok_, unsigned short* __restrict__ ov,
    const float* __restrict__ w0, const float* __restrict__ w1,
    const float* __restrict__ w2, const float* __restrict__ w3,
    unsigned short* __restrict__ t0, unsigned short* __restrict__ t1,
    unsigned short* __restrict__ t2, unsigned short* __restrict__ t3) {
    __shared__ float tile[64][65];
    const int bx = blockIdx.x, t = threadIdx.x;
    if (bx < 6144) {              // cvt part: 3 slabs x 2048 blocks
        const int slab = bx >> 11, bxr = bx & 2047;
        const float* in = slab == 0 ? q : (slab == 1 ? k : v);
        unsigned short* out = slab == 0 ? oq : (slab == 1 ? ok_ : ov);
        size_t i = ((size_t)bxr * 256 + t) * 8;
        float4v a = *(const float4v*)(in + i);
        float4v b = *(const float4v*)(in + i + 4);
        u16x8 r;
        r[0]=f2bf(a[0]); r[1]=f2bf(a[1]); r[2]=f2bf(a[2]); r[3]=f2bf(a[3]);
        r[4]=f2bf(b[0]); r[5]=f2bf(b[1]); r[6]=f2bf(b[2]); r[7]=f2bf(b[3]);
        *(u16x8*)(out + i) = r;
    } else {                      // wtrans part: 4 weights x 256 tiles
        const int i2 = bx - 6144;
        const int z = i2 >> 8, rem = i2 & 255;
        const float* w = z==0 ? w0 : z==1 ? w1 : z==2 ? w2 : w3;
        unsigned short* wt = z==0 ? t0 : z==1 ? t1 : z==2 ? t2 : t3;
        const int k0 = (rem & 15) * 64, n0 = (rem >> 4) * 64;
        const int tr = t >> 4, tc = t & 15;
#pragma unroll
        for (int i = 0; i < 4; ++i) {
            float4v val = *(const float4v*)(w + (size_t)(k0 + tr + 16*i) * DM + n0 + tc*4);
            tile[tr + 16*i][tc*4 + 0] = val[0];
            tile[tr + 16*i][tc*4 + 1] = val[1];
            tile[tr + 16*i][tc*4 + 2] = val[2];
            tile[tr + 16*i][tc*4 + 3] = val[3];
        }
        __syncthreads();
#pragma unroll
        for (int i = 0; i < 4; ++i) {
            u16x4 o;
#pragma unroll
            for (int j = 0; j < 4; ++j) o[j] = f2bf(tile[tc*4 + j][tr + 16*i]);
            *(u16x4*)(wt + (size_t)(n0 + tr + 16*i) * DM + k0 + tc*4) = o;
        }
    }
}

// ---------------- GEMM body: BM=128, BN=64; OUTMODE 0 bf16, 1 f32, 2 per-head-V^T ----------------
template<int OUTMODE>
static __device__ __forceinline__ void gemm_body(
    const unsigned short* __restrict__ A, const unsigned short* __restrict__ Bt,
    const float* __restrict__ bias, void* __restrict__ Cout,
    unsigned short* a_lds, unsigned short* b_lds) {
    constexpr int BM = 128, BN = 64, BK = 64, NT = DM / BK;
    const int tid = threadIdx.x;
    const int m0 = blockIdx.y * BM, n0 = blockIdx.x * BN;
    const int w = tid >> 6, l = tid & 63;
    const int lr = l & 15, lg = l >> 4;
    const int wm = (w >> 1) * 64, wn = (w & 1) * 32;
    f32x4 acc[4][2] = {};

    auto stage = [&](int buf, int kt) {
        const int k0 = kt * BK;
#pragma unroll
        for (int i = 0; i < 4; ++i) {
            int u = i*256 + tid;
            int row = u >> 3, slot = u & 7;
            int sc = (slot ^ (row & 7)) * 8;
            GLDS16(A + (size_t)(m0 + row)*DM + k0 + sc, a_lds + buf*BM*BK + u*8);
        }
#pragma unroll
        for (int i = 0; i < 2; ++i) {
            int u = i*256 + tid;
            int row = u >> 3, slot = u & 7;
            int sc = (slot ^ (row & 7)) * 8;
            GLDS16(Bt + (size_t)(n0 + row)*DM + k0 + sc, b_lds + buf*BN*BK + u*8);
        }
    };

    stage(0, 0);
    for (int kt = 0; kt < NT; ++kt) {
        __syncthreads();
        if (kt < NT-1) stage((kt+1)&1, kt+1);
        const char* ab = (const char*)(a_lds + (kt&1)*BM*BK);
        const char* bb = (const char*)(b_lds + (kt&1)*BN*BK);
        bf16x8 af[4][2], bfr[2][2];
#pragma unroll
        for (int r = 0; r < 4; ++r)
#pragma unroll
            for (int kc = 0; kc < 2; ++kc) {
                int row = wm + r*16 + lr;
                af[r][kc] = *(const bf16x8*)(ab + row*128 + ((kc*64 + lg*16) ^ ((row&7)<<4)));
            }
#pragma unroll
        for (int c = 0; c < 2; ++c)
#pragma unroll
            for (int kc = 0; kc < 2; ++kc) {
                int row = wn + c*16 + lr;
                bfr[c][kc] = *(const bf16x8*)(bb + row*128 + ((kc*64 + lg*16) ^ ((row&7)<<4)));
            }
#pragma unroll
        for (int r = 0; r < 4; ++r)
#pragma unroll
            for (int c = 0; c < 2; ++c)
#pragma unroll
                for (int kc = 0; kc < 2; ++kc)
                    acc[r][c] = __builtin_amdgcn_mfma_f32_16x16x32_bf16(af[r][kc], bfr[c][kc], acc[r][c], 0, 0, 0);
    }

#pragma unroll
    for (int r = 0; r < 4; ++r)
#pragma unroll
        for (int c = 0; c < 2; ++c) {
            int m = m0 + wm + r*16 + lg*4;
            int n = n0 + wn + c*16 + lr;
            float bb = bias[n];
            if constexpr (OUTMODE == 1) {
                float* o = (float*)Cout;
#pragma unroll
                for (int j = 0; j < 4; ++j) o[(size_t)(m+j)*DM + n] = acc[r][c][j] + bb;
            } else if constexpr (OUTMODE == 0) {
                unsigned short* o = (unsigned short*)Cout;
#pragma unroll
                for (int j = 0; j < 4; ++j) o[(size_t)(m+j)*DM + n] = f2bf(acc[r][c][j] + bb);
            } else {
                // per-head V^T: vtg[(b*16 + n/64)*64 + n%64][k], k = m % SEQ (4 contiguous)
                unsigned short* o = (unsigned short*)Cout;
                int bb_ = m >> 11, kk = m & (SEQ-1);
                int bh = bb_ * NH + (n >> 6), d = n & 63;
                u16x4 ov;
#pragma unroll
                for (int j = 0; j < 4; ++j) ov[j] = f2bf(acc[r][c][j] + bb);
                *(u16x4*)(o + ((size_t)bh*DH + d)*SEQ + kk) = ov;
            }
        }
}

__global__ __launch_bounds__(256, 3) void gemm_qkv_kernel(
    const unsigned short* __restrict__ A0, const unsigned short* __restrict__ A1, const unsigned short* __restrict__ A2,
    const unsigned short* __restrict__ B0, const unsigned short* __restrict__ B1, const unsigned short* __restrict__ B2,
    const float* __restrict__ c0, const float* __restrict__ c1, const float* __restrict__ c2,
    unsigned short* __restrict__ O0, unsigned short* __restrict__ O1, unsigned short* __restrict__ O2) {
    __shared__ __align__(16) unsigned short smem[2*128*64 + 2*64*64];   // 48 KB
    const int z = blockIdx.z;
    const unsigned short* A = z==0 ? A0 : z==1 ? A1 : A2;
    const unsigned short* B = z==0 ? B0 : z==1 ? B1 : B2;
    const float* c = z==0 ? c0 : z==1 ? c1 : c2;
    unsigned short* O = z==0 ? O0 : z==1 ? O1 : O2;
    if (z == 2) gemm_body<2>(A, B, c, O, smem, smem + 2*128*64);
    else        gemm_body<0>(A, B, c, O, smem, smem + 2*128*64);
}

__global__ __launch_bounds__(256, 3) void gemm_out_kernel(
    const unsigned short* __restrict__ A, const unsigned short* __restrict__ Bt,
    const float* __restrict__ bias, float* __restrict__ Cout) {
    __shared__ __align__(16) unsigned short smem[2*128*64 + 2*64*64];   // 48 KB
    gemm_body<1>(A, Bt, bias, Cout, smem, smem + 2*128*64);
}

// ---------------- attn_den: softmax denominators only ----------------
__global__ __launch_bounds__(512, 6) void attn_den_kernel(
    const unsigned short* __restrict__ qw, const unsigned short* __restrict__ kw,
    const float* __restrict__ mask, float* __restrict__ rinv_out) {
    constexpr int QB = 128, KB = 64, NT2 = SEQ / KB / 2;
    __shared__ __align__(16) unsigned short smem[4*KB*DH + 4096];   // 32 KB K dbuf + 8 KB mask
    unsigned short* kbuf = smem;
    float* madd_f = (float*)(smem + 4*KB*DH);
    const int tid = threadIdx.x, w = tid >> 6, l = tid & 63;
    const int hh = w >> 2, ws = w & 3;
    const int q32 = l & 31, hi = l >> 5;
    const int u0 = (blockIdx.x & 7) * 64 + (blockIdx.x >> 3);
    const int qblk = u0 & 15, bh = u0 >> 4;
    const int b = bh >> 4, h = bh & 15;
    const int q0 = qblk * QB;
    const int q = q0 + ws*32 + q32;
    const int kbase = hh * (SEQ/2);

    {
        int idx = tid * 4;
        float4v m4 = *(const float4v*)(mask + (size_t)b*SEQ + idx);
        float4v md;
#pragma unroll
        for (int r = 0; r < 4; ++r) md[r] = (1.0f - m4[r]) * (-1e9f);
        *(float4v*)(madd_f + idx) = md;
    }

    bf16x8 qf[4];
    {
        const unsigned short* qp = qw + ((size_t)(b*SEQ + q))*DM + h*DH + hi*8;
#pragma unroll
        for (int ks = 0; ks < 4; ++ks) {
            bf16x8 t = *(const bf16x8*)(qp + ks*16);
#pragma unroll
            for (int j = 0; j < 8; ++j) t[j] = (short)f2bf(bf2f((unsigned short)t[j]) * 0.125f);
            qf[ks] = t;
        }
    }

    auto stageK = [&](int buf, int kt) {
#pragma unroll
        for (int hf = 0; hf < 2; ++hf) {
            int row = tid >> 3, slot = tid & 7;
            int sc = (slot ^ (row & 7)) * 8;
            const unsigned short* base = kw + ((size_t)(b*SEQ + hf*(SEQ/2) + kt*KB + row))*DM + h*DH;
            GLDS16(base + sc, kbuf + (buf*2 + hf)*KB*DH + tid*8);
        }
    };

    float rs = 0.f;
    stageK(0, 0);
    for (int kt = 0; kt < NT2; ++kt) {
        __syncthreads();
        if (kt < NT2-1) stageK((kt+1)&1, kt+1);
        const char* kb = (const char*)(kbuf + ((kt&1)*2 + hh)*KB*DH);
#pragma unroll
        for (int sub = 0; sub < 2; ++sub) {
            f32x16 s = {};
#pragma unroll
            for (int ks = 0; ks < 4; ++ks) {
                int key = sub*32 + q32;
                bf16x8 kf = *(const bf16x8*)(kb + key*128 + ((ks*32 + hi*16) ^ ((key&7)<<4)));
                s = __builtin_amdgcn_mfma_f32_32x32x16_bf16(kf, qf[ks], s, 0, 0, 0);
            }
#pragma unroll
            for (int rq = 0; rq < 4; ++rq) {
                float4v m4 = *(const float4v*)(madd_f + kbase + kt*KB + sub*32 + rq*8 + hi*4);
#pragma unroll
                for (int r = 0; r < 4; ++r)
                    rs += __expf(s[rq*4 + r] + m4[r]);
            }
        }
    }
    rs += __shfl_xor(rs, 32);
    float* rbuf = (float*)smem;
    __syncthreads();
    rbuf[w*64 + l] = rs;
    __syncthreads();
    rs += rbuf[(w ^ 4)*64 + l];
    if (hh == 0 && l < 32)
        rinv_out[(size_t)bh*SEQ + q] = 1.0f / rs;
}

// ---------------- attn_out: probabilities (coalesced via wave-local LDS transpose) + PV --------
__global__ __launch_bounds__(512, 4) void attn_out_kernel(
    const unsigned short* __restrict__ qw, const unsigned short* __restrict__ kw,
    const unsigned short* __restrict__ vtg, const float* __restrict__ mask,
    const float* __restrict__ rinv_g, float* __restrict__ attn_out,
    unsigned short* __restrict__ ctx) {
    constexpr int QB = 128, KB = 64, NT2 = SEQ / KB / 2;
    // 32 KB kbuf + 32 KB vbuf + 16 KB pbuf (8 waves x 2 KB) = 80 KB (2 blocks/CU)
    __shared__ __align__(16) unsigned short smem[4*KB*DH + 4*KB*DH + 8192];
    unsigned short* kbuf = smem;
    unsigned short* vbuf = smem + 4*KB*DH;
    float* pbuf = (float*)(smem + 8*KB*DH);       // [8 waves][16 rows][32 cols] f32, XOR-swizzled
    const int tid = threadIdx.x, w = tid >> 6, l = tid & 63;
    const int hh = w >> 2, ws = w & 3;
    const int q32 = l & 31, hi = l >> 5;
    const int u0 = (blockIdx.x & 7) * 64 + (blockIdx.x >> 3);
    const int qblk = u0 & 15, bh = u0 >> 4;
    const int b = bh >> 4, h = bh & 15;
    const int q0 = qblk * QB;
    const int q = q0 + ws*32 + q32;
    const int kbase = hh * (SEQ/2);
    const float rinv = rinv_g[(size_t)bh*SEQ + q];
    char* pw = (char*)(pbuf + w*512);             // this wave's 2 KB transpose buffer

    bf16x8 qf[4];
    {
        const unsigned short* qp = qw + ((size_t)(b*SEQ + q))*DM + h*DH + hi*8;
#pragma unroll
        for (int ks = 0; ks < 4; ++ks) {
            bf16x8 t = *(const bf16x8*)(qp + ks*16);
#pragma unroll
            for (int j = 0; j < 8; ++j) t[j] = (short)f2bf(bf2f((unsigned short)t[j]) * 0.125f);
            qf[ks] = t;
        }
    }

    auto stageK = [&](int buf, int kt) {
#pragma unroll
        for (int hf = 0; hf < 2; ++hf) {
            int row = tid >> 3, slot = tid & 7;
            int sc = (slot ^ (row & 7)) * 8;
            const unsigned short* base = kw + ((size_t)(b*SEQ + hf*(SEQ/2) + kt*KB + row))*DM + h*DH;
            GLDS16(base + sc, kbuf + (buf*2 + hf)*KB*DH + tid*8);
        }
    };
    auto stageV = [&](int buf, int kt) {
#pragma unroll
        for (int hf = 0; hf < 2; ++hf) {
            int row = tid >> 3, slot = tid & 7;
            int sc = (slot ^ (row & 7)) * 8;
            const unsigned short* base = vtg + ((size_t)bh*DH + row)*SEQ + hf*(SEQ/2) + kt*KB;
            GLDS16(base + sc, vbuf + (buf*2 + hf)*KB*DH + tid*8);
        }
    };

    const float* mrow = mask + (size_t)b*SEQ + kbase;
    // coalesced-store lane roles: 8 lanes per row, float4 each
    const int srow = l >> 3;                      // row-within-8 for store reads
    const int scol16 = (l & 7) * 16;              // byte col offset (4 floats)

    f32x16 oacc[2] = {};
    float* attn_base = attn_out + ((size_t)bh*SEQ + q0 + ws*32)*SEQ + kbase;
    stageK(0, 0); stageV(0, 0);
    for (int kt = 0; kt < NT2; ++kt) {
        __syncthreads();
        if (kt < NT2-1) { stageK((kt+1)&1, kt+1); stageV((kt+1)&1, kt+1); }
        const char* kb = (const char*)(kbuf + ((kt&1)*2 + hh)*KB*DH);
        const char* vb = (const char*)(vbuf + ((kt&1)*2 + hh)*KB*DH);
#pragma unroll
        for (int sub = 0; sub < 2; ++sub) {
            f32x16 s = {};
#pragma unroll
            for (int ks = 0; ks < 4; ++ks) {
                int key = sub*32 + q32;
                bf16x8 kf = *(const bf16x8*)(kb + key*128 + ((ks*32 + hi*16) ^ ((key&7)<<4)));
                s = __builtin_amdgcn_mfma_f32_32x32x16_bf16(kf, qf[ks], s, 0, 0, 0);
            }
            // probabilities: pf[rq] = cols sub*32 + rq*8 + hi*4 + 0..3 of row q
            float4v pf[4];
#pragma unroll
            for (int rq = 0; rq < 4; ++rq) {
                float4v m4 = *(const float4v*)(mrow + kt*KB + sub*32 + rq*8 + hi*4);
#pragma unroll
                for (int r = 0; r < 4; ++r)
                    pf[rq][r] = __expf(s[rq*4 + r] + (1.0f - m4[r]) * (-1e9f)) * rinv;
            }
            // PV via cvt_pk + permlane32_swap (unchanged register path)
#pragma unroll
            for (int half = 0; half < 2; ++half) {
                unsigned int w0 = cvt_pk_bf16(pf[half*2][0], pf[half*2][1]);
                unsigned int w1 = cvt_pk_bf16(pf[half*2][2], pf[half*2][3]);
                unsigned int w2 = cvt_pk_bf16(pf[half*2+1][0], pf[half*2+1][1]);
                unsigned int w3 = cvt_pk_bf16(pf[half*2+1][2], pf[half*2+1][3]);
                asm volatile("v_permlane32_swap_b32 %0, %1" : "+v"(w0), "+v"(w2));
                asm volatile("v_permlane32_swap_b32 %0, %1" : "+v"(w1), "+v"(w3));
                union { unsigned int uu[4]; bf16x8 v; } pa;
                pa.uu[0] = w0; pa.uu[1] = w1; pa.uu[2] = w2; pa.uu[3] = w3;
                const int ks4 = sub*2 + half;
#pragma unroll
                for (int dsub = 0; dsub < 2; ++dsub) {
                    int d = dsub*32 + q32;
                    bf16x8 vf = *(const bf16x8*)(vb + d*128 + ((ks4*32 + hi*16) ^ ((d&7)<<4)));
                    oacc[dsub] = __builtin_amdgcn_mfma_f32_32x32x16_bf16(pa.v, vf, oacc[dsub], 0, 0, 0);
                }
            }
            // coalesced attn store: wave-local transpose through pbuf.
            // chunk c covers rows c*16..c*16+15 of this wave's 32 q-rows.
#pragma unroll
            for (int c = 0; c < 2; ++c) {
                if ((q32 >> 4) == c) {
                    int row16 = q32 & 15;
#pragma unroll
                    for (int rq = 0; rq < 4; ++rq) {
                        int off = row16*128 + ((rq*32 + hi*16) ^ ((row16 & 7) << 4));
                        *(float4v*)(pw + off) = pf[rq];
                    }
                }
                lds_fence();   // cross-lane write -> read handoff (R10's missing edge)
#pragma unroll
                for (int i = 0; i < 2; ++i) {
                    int row16r = i*8 + srow;
                    int off = row16r*128 + (scol16 ^ ((row16r & 7) << 4));
                    float4v val = *(const float4v*)(pw + off);
                    *(float4v*)(attn_base + (size_t)(c*16 + row16r)*SEQ
                                + kt*KB + sub*32 + (l & 7)*4) = val;
                }
                lds_fence();   // reads complete before next chunk overwrites (WAR)
            }
        }
    }

    // combine ctx partials across key-half wave pairs (stride 36 dodges bank conflicts)
    float* cbuf = (float*)smem;
    __syncthreads();
    if (w >= 4) {
        int base = ((w - 4)*64 + l) * 36;
        *(f32x16*)(cbuf + base) = oacc[0];
        *(f32x16*)(cbuf + base + 16) = oacc[1];
    }
    __syncthreads();
    if (w < 4) {
        int base = (w*64 + l) * 36;
        oacc[0] += *(const f32x16*)(cbuf + base);
        oacc[1] += *(const f32x16*)(cbuf + base + 16);
#pragma unroll
        for (int dsub = 0; dsub < 2; ++dsub) {
            int d = h*DH + dsub*32 + q32;
#pragma unroll
            for (int reg = 0; reg < 16; ++reg) {
                int qr = q0 + ws*32 + (reg&3) + 8*(reg>>2) + 4*hi;
                ctx[(size_t)(b*SEQ + qr)*DM + d] = f2bf(oacc[dsub][reg]);
            }
        }
    }
}

extern "C" void kernel_launch(void* const* d_in, const int* in_sizes, int n_in,
                              void* d_out, int out_size, void* d_ws, size_t ws_size,
                              hipStream_t stream) {
    const float* query = (const float*)d_in[0];
    const float* key_  = (const float*)d_in[1];
    const float* value = (const float*)d_in[2];
    const float* mask  = (const float*)d_in[3];
    const float* W_q = (const float*)d_in[4];
    const float* b_q = (const float*)d_in[5];
    const float* W_k = (const float*)d_in[6];
    const float* b_k = (const float*)d_in[7];
    const float* W_v = (const float*)d_in[8];
    const float* b_v = (const float*)d_in[9];
    const float* W_o = (const float*)d_in[10];
    const float* b_o = (const float*)d_in[11];

    char* ws = (char*)d_ws;
    const size_t SZ = (size_t)MTOT * DM * 2;          // 8 MiB per bf16 [4096][1024]
    unsigned short* xq  = (unsigned short*)(ws);
    unsigned short* xk  = (unsigned short*)(ws + SZ);
    unsigned short* xv  = (unsigned short*)(ws + 2*SZ);
    unsigned short* wtq = (unsigned short*)(ws + 3*SZ);
    unsigned short* wtk = wtq + (size_t)DM*DM;
    unsigned short* wtv = wtk + (size_t)DM*DM;
    unsigned short* wto = wtv + (size_t)DM*DM;
    unsigned short* qws = (unsigned short*)(ws + 4*SZ);
    unsigned short* kws = (unsigned short*)(ws + 5*SZ);
    unsigned short* vtg = (unsigned short*)(ws + 6*SZ);  // per-head V^T from gemm_qkv z=2
    unsigned short* ctx = (unsigned short*)(ws + 7*SZ);
    float* rinv = (float*)(ws + 8*SZ);                   // [32][2048] = 256 KB
    float* out_f  = (float*)d_out;
    float* attn_f = out_f + (size_t)MTOT * DM;

    prep_kernel<<<dim3(7168), 256, 0, stream>>>(query, key_, value, xq, xk, xv,
                                                W_q, W_k, W_v, W_o, wtq, wtk, wtv, wto);
    gemm_qkv_kernel<<<dim3(16, 32, 3), 256, 0, stream>>>(xq, xk, xv, wtq, wtk, wtv,
                                                         b_q, b_k, b_v, qws, kws, vtg);
    attn_den_kernel<<<dim3(512), 512, 0, stream>>>(qws, kws, mask, rinv);
    attn_out_kernel<<<dim3(512), 512, 0, stream>>>(qws, kws, vtg, mask, rinv, attn_f, ctx);
    gemm_out_kernel<<<dim3(16, 32), 256, 0, stream>>>(ctx, wto, b_o, out_f);
}

// Round 12
// 272.665 us; speedup vs baseline: 2.5586x; 1.0180x over previous
//
#include <hip/hip_runtime.h>
#include <hip/hip_bf16.h>

#define BATCH 2
#define SEQ 2048
#define DM 1024
#define NH 16
#define DH 64
#define MTOT (BATCH*SEQ)

typedef __attribute__((ext_vector_type(8))) short bf16x8;
typedef __attribute__((ext_vector_type(4))) float f32x4;
typedef __attribute__((ext_vector_type(16))) float f32x16;
typedef __attribute__((ext_vector_type(4))) float float4v;
typedef __attribute__((ext_vector_type(8))) unsigned short u16x8;
typedef __attribute__((ext_vector_type(4))) unsigned short u16x4;

#define GLDS16(g, l) __builtin_amdgcn_global_load_lds(                         \
    (const __attribute__((address_space(1))) void*)(g),                        \
    (__attribute__((address_space(3))) void*)(l), 16, 0, 0)

static __device__ __forceinline__ float bf2f(unsigned short u) {
    unsigned int x = ((unsigned int)u) << 16;
    float f; __builtin_memcpy(&f, &x, 4); return f;
}
static __device__ __forceinline__ unsigned short f2bf(float f) {
    unsigned int x; __builtin_memcpy(&x, &f, 4);
    x += 0x7fffu + ((x >> 16) & 1);   // RNE
    return (unsigned short)(x >> 16);
}
static __device__ __forceinline__ unsigned int cvt_pk_bf16(float a, float b) {
    unsigned int r;
    asm volatile("v_cvt_pk_bf16_f32 %0, %1, %2" : "=v"(r) : "v"(a), "v"(b));
    return r;
}
// Cross-lane same-wave LDS handoff fence (R10 bug fix): plain HIP has no
// dependence edge for lane A ds_write -> lane B ds_read within a wave.
static __device__ __forceinline__ void lds_fence() {
    __builtin_amdgcn_wave_barrier();
    asm volatile("s_waitcnt lgkmcnt(0)" ::: "memory");
    __builtin_amdgcn_sched_barrier(0);
}

// ---------------- prep: fused {q,k,v fp32->bf16} + {W^T fp32->bf16} ----------------
__global__ __launch_bounds__(256) void prep_kernel(
    const float* __restrict__ q, const float* __restrict__ k, const float* __restrict__ v,
    unsigned short* __restrict__ oq, unsigned short* __restrict__ ok_, unsigned short* __restrict__ ov,
    const float* __restrict__ w0, const float* __restrict__ w1,
    const float* __restrict__ w2, const float* __restrict__ w3,
    unsigned short* __restrict__ t0, unsigned short* __restrict__ t1,
    unsigned short* __restrict__ t2, unsigned short* __restrict__ t3) {
    __shared__ float tile[64][65];
    const int bx = blockIdx.x, t = threadIdx.x;
    if (bx < 6144) {              // cvt part: 3 slabs x 2048 blocks
        const int slab = bx >> 11, bxr = bx & 2047;
        const float* in = slab == 0 ? q : (slab == 1 ? k : v);
        unsigned short* out = slab == 0 ? oq : (slab == 1 ? ok_ : ov);
        size_t i = ((size_t)bxr * 256 + t) * 8;
        float4v a = *(const float4v*)(in + i);
        float4v b = *(const float4v*)(in + i + 4);
        u16x8 r;
        r[0]=f2bf(a[0]); r[1]=f2bf(a[1]); r[2]=f2bf(a[2]); r[3]=f2bf(a[3]);
        r[4]=f2bf(b[0]); r[5]=f2bf(b[1]); r[6]=f2bf(b[2]); r[7]=f2bf(b[3]);
        *(u16x8*)(out + i) = r;
    } else {                      // wtrans part: 4 weights x 256 tiles
        const int i2 = bx - 6144;
        const int z = i2 >> 8, rem = i2 & 255;
        const float* w = z==0 ? w0 : z==1 ? w1 : z==2 ? w2 : w3;
        unsigned short* wt = z==0 ? t0 : z==1 ? t1 : z==2 ? t2 : t3;
        const int k0 = (rem & 15) * 64, n0 = (rem >> 4) * 64;
        const int tr = t >> 4, tc = t & 15;
#pragma unroll
        for (int i = 0; i < 4; ++i) {
            float4v val = *(const float4v*)(w + (size_t)(k0 + tr + 16*i) * DM + n0 + tc*4);
            tile[tr + 16*i][tc*4 + 0] = val[0];
            tile[tr + 16*i][tc*4 + 1] = val[1];
            tile[tr + 16*i][tc*4 + 2] = val[2];
            tile[tr + 16*i][tc*4 + 3] = val[3];
        }
        __syncthreads();
#pragma unroll
        for (int i = 0; i < 4; ++i) {
            u16x4 o;
#pragma unroll
            for (int j = 0; j < 4; ++j) o[j] = f2bf(tile[tc*4 + j][tr + 16*i]);
            *(u16x4*)(wt + (size_t)(n0 + tr + 16*i) * DM + k0 + tc*4) = o;
        }
    }
}

// ---------------- GEMM body: BM=128, BN=64; OUTMODE 0 bf16, 1 f32, 2 per-head-V^T ----------------
template<int OUTMODE>
static __device__ __forceinline__ void gemm_body(
    const unsigned short* __restrict__ A, const unsigned short* __restrict__ Bt,
    const float* __restrict__ bias, void* __restrict__ Cout,
    unsigned short* a_lds, unsigned short* b_lds) {
    constexpr int BM = 128, BN = 64, BK = 64, NT = DM / BK;
    const int tid = threadIdx.x;
    const int m0 = blockIdx.y * BM, n0 = blockIdx.x * BN;
    const int w = tid >> 6, l = tid & 63;
    const int lr = l & 15, lg = l >> 4;
    const int wm = (w >> 1) * 64, wn = (w & 1) * 32;
    f32x4 acc[4][2] = {};

    auto stage = [&](int buf, int kt) {
        const int k0 = kt * BK;
#pragma unroll
        for (int i = 0; i < 4; ++i) {
            int u = i*256 + tid;
            int row = u >> 3, slot = u & 7;
            int sc = (slot ^ (row & 7)) * 8;
            GLDS16(A + (size_t)(m0 + row)*DM + k0 + sc, a_lds + buf*BM*BK + u*8);
        }
#pragma unroll
        for (int i = 0; i < 2; ++i) {
            int u = i*256 + tid;
            int row = u >> 3, slot = u & 7;
            int sc = (slot ^ (row & 7)) * 8;
            GLDS16(Bt + (size_t)(n0 + row)*DM + k0 + sc, b_lds + buf*BN*BK + u*8);
        }
    };

    stage(0, 0);
    for (int kt = 0; kt < NT; ++kt) {
        __syncthreads();
        if (kt < NT-1) stage((kt+1)&1, kt+1);
        const char* ab = (const char*)(a_lds + (kt&1)*BM*BK);
        const char* bb = (const char*)(b_lds + (kt&1)*BN*BK);
        bf16x8 af[4][2], bfr[2][2];
#pragma unroll
        for (int r = 0; r < 4; ++r)
#pragma unroll
            for (int kc = 0; kc < 2; ++kc) {
                int row = wm + r*16 + lr;
                af[r][kc] = *(const bf16x8*)(ab + row*128 + ((kc*64 + lg*16) ^ ((row&7)<<4)));
            }
#pragma unroll
        for (int c = 0; c < 2; ++c)
#pragma unroll
            for (int kc = 0; kc < 2; ++kc) {
                int row = wn + c*16 + lr;
                bfr[c][kc] = *(const bf16x8*)(bb + row*128 + ((kc*64 + lg*16) ^ ((row&7)<<4)));
            }
#pragma unroll
        for (int r = 0; r < 4; ++r)
#pragma unroll
            for (int c = 0; c < 2; ++c)
#pragma unroll
                for (int kc = 0; kc < 2; ++kc)
                    acc[r][c] = __builtin_amdgcn_mfma_f32_16x16x32_bf16(af[r][kc], bfr[c][kc], acc[r][c], 0, 0, 0);
    }

#pragma unroll
    for (int r = 0; r < 4; ++r)
#pragma unroll
        for (int c = 0; c < 2; ++c) {
            int m = m0 + wm + r*16 + lg*4;
            int n = n0 + wn + c*16 + lr;
            float bb = bias[n];
            if constexpr (OUTMODE == 1) {
                float* o = (float*)Cout;
#pragma unroll
                for (int j = 0; j < 4; ++j) o[(size_t)(m+j)*DM + n] = acc[r][c][j] + bb;
            } else if constexpr (OUTMODE == 0) {
                unsigned short* o = (unsigned short*)Cout;
#pragma unroll
                for (int j = 0; j < 4; ++j) o[(size_t)(m+j)*DM + n] = f2bf(acc[r][c][j] + bb);
            } else {
                // per-head V^T: vtg[(b*16 + n/64)*64 + n%64][k], k = m % SEQ (4 contiguous)
                unsigned short* o = (unsigned short*)Cout;
                int bb_ = m >> 11, kk = m & (SEQ-1);
                int bh = bb_ * NH + (n >> 6), d = n & 63;
                u16x4 ov;
#pragma unroll
                for (int j = 0; j < 4; ++j) ov[j] = f2bf(acc[r][c][j] + bb);
                *(u16x4*)(o + ((size_t)bh*DH + d)*SEQ + kk) = ov;
            }
        }
}

__global__ __launch_bounds__(256, 3) void gemm_qkv_kernel(
    const unsigned short* __restrict__ A0, const unsigned short* __restrict__ A1, const unsigned short* __restrict__ A2,
    const unsigned short* __restrict__ B0, const unsigned short* __restrict__ B1, const unsigned short* __restrict__ B2,
    const float* __restrict__ c0, const float* __restrict__ c1, const float* __restrict__ c2,
    unsigned short* __restrict__ O0, unsigned short* __restrict__ O1, unsigned short* __restrict__ O2) {
    __shared__ __align__(16) unsigned short smem[2*128*64 + 2*64*64];   // 48 KB
    const int z = blockIdx.z;
    const unsigned short* A = z==0 ? A0 : z==1 ? A1 : A2;
    const unsigned short* B = z==0 ? B0 : z==1 ? B1 : B2;
    const float* c = z==0 ? c0 : z==1 ? c1 : c2;
    unsigned short* O = z==0 ? O0 : z==1 ? O1 : O2;
    if (z == 2) gemm_body<2>(A, B, c, O, smem, smem + 2*128*64);
    else        gemm_body<0>(A, B, c, O, smem, smem + 2*128*64);
}

__global__ __launch_bounds__(256, 3) void gemm_out_kernel(
    const unsigned short* __restrict__ A, const unsigned short* __restrict__ Bt,
    const float* __restrict__ bias, float* __restrict__ Cout) {
    __shared__ __align__(16) unsigned short smem[2*128*64 + 2*64*64];   // 48 KB
    gemm_body<1>(A, Bt, bias, Cout, smem, smem + 2*128*64);
}

// ---------------- Attention (fused two-pass): den pass + coalesced-store out pass ----------------
// 8 waves: waves 0-3 q-slabs x keys 0..1023, waves 4-7 same slabs x keys 1024..2047.
// LDS: 32K kbuf + 32K vbuf + 16K pbuf = 80 KB -> 2 blocks/CU; blocks drift out of
// phase so one block's pass-1 (read/MFMA) overlaps the other's pass-2 (write-heavy).
__global__ __launch_bounds__(512, 4) void attn_kernel(
    const unsigned short* __restrict__ qw, const unsigned short* __restrict__ kw,
    const unsigned short* __restrict__ vtg, const float* __restrict__ mask,
    float* __restrict__ attn_out, unsigned short* __restrict__ ctx) {
    constexpr int QB = 128, KB = 64, NT2 = SEQ / KB / 2;   // 16 tiles per half
    __shared__ __align__(16) unsigned short smem[4*KB*DH + 4*KB*DH + 8192];  // 80 KB
    unsigned short* kbuf = smem;                  // [buf][half][64 key][64 k]
    unsigned short* vbuf = smem + 4*KB*DH;        // [buf][half][64 d][64 key]
    float* pbuf = (float*)(smem + 8*KB*DH);       // [8 waves][16 rows][32 cols] f32, XOR-swizzled
    const int tid = threadIdx.x, w = tid >> 6, l = tid & 63;
    const int hh = w >> 2, ws = w & 3;            // key-half, q-slab
    const int q32 = l & 31, hi = l >> 5;
    const int u0 = (blockIdx.x & 7) * 64 + (blockIdx.x >> 3);  // XCD-chunked
    const int qblk = u0 & 15, bh = u0 >> 4;
    const int b = bh >> 4, h = bh & 15;
    const int q0 = qblk * QB;
    const int q = q0 + ws*32 + q32;
    const int kbase = hh * (SEQ/2);
    char* pw = (char*)(pbuf + w*512);             // this wave's 2 KB transpose buffer

    bf16x8 qf[4];
    {
        const unsigned short* qp = qw + ((size_t)(b*SEQ + q))*DM + h*DH + hi*8;
#pragma unroll
        for (int ks = 0; ks < 4; ++ks) {
            bf16x8 t = *(const bf16x8*)(qp + ks*16);
#pragma unroll
            for (int j = 0; j < 8; ++j) t[j] = (short)f2bf(bf2f((unsigned short)t[j]) * 0.125f);
            qf[ks] = t;
        }
    }

    auto stageK = [&](int buf, int kt) {
#pragma unroll
        for (int hf = 0; hf < 2; ++hf) {
            int row = tid >> 3, slot = tid & 7;
            int sc = (slot ^ (row & 7)) * 8;
            const unsigned short* base = kw + ((size_t)(b*SEQ + hf*(SEQ/2) + kt*KB + row))*DM + h*DH;
            GLDS16(base + sc, kbuf + (buf*2 + hf)*KB*DH + tid*8);
        }
    };
    auto stageV = [&](int buf, int kt) {
#pragma unroll
        for (int hf = 0; hf < 2; ++hf) {
            int row = tid >> 3, slot = tid & 7;           // row = d
            int sc = (slot ^ (row & 7)) * 8;
            const unsigned short* base = vtg + ((size_t)bh*DH + row)*SEQ + hf*(SEQ/2) + kt*KB;
            GLDS16(base + sc, vbuf + (buf*2 + hf)*KB*DH + tid*8);
        }
    };

    const float* mrow = mask + (size_t)b*SEQ + kbase;

    // ---- pass 1: partial softmax denominator over this wave's key half ----
    float rs = 0.f;
    stageK(0, 0);
    for (int kt = 0; kt < NT2; ++kt) {
        __syncthreads();
        if (kt < NT2-1) stageK((kt+1)&1, kt+1);
        const char* kb = (const char*)(kbuf + ((kt&1)*2 + hh)*KB*DH);
#pragma unroll
        for (int sub = 0; sub < 2; ++sub) {
            f32x16 s = {};
#pragma unroll
            for (int ks = 0; ks < 4; ++ks) {
                int key = sub*32 + q32;
                bf16x8 kf = *(const bf16x8*)(kb + key*128 + ((ks*32 + hi*16) ^ ((key&7)<<4)));
                s = __builtin_amdgcn_mfma_f32_32x32x16_bf16(kf, qf[ks], s, 0, 0, 0);
            }
#pragma unroll
            for (int rq = 0; rq < 4; ++rq) {
                float4v m4 = *(const float4v*)(mrow + kt*KB + sub*32 + rq*8 + hi*4);
#pragma unroll
                for (int r = 0; r < 4; ++r)
                    rs += __expf(s[rq*4 + r] + (1.0f - m4[r]) * (-1e9f));
            }
        }
    }
    rs += __shfl_xor(rs, 32);
    // combine across key-half wave pairs via LDS (pbuf region; pass 2 restages below)
    {
        float* rbuf = (float*)pbuf;
        __syncthreads();
        rbuf[w*64 + l] = rs;
        __syncthreads();
        rs += rbuf[(w ^ 4)*64 + l];
        __syncthreads();
    }
    const float rinv = 1.0f / rs;

    // ---- pass 2: attn write (coalesced via fenced wave-local transpose) + PV ----
    const int srow = l >> 3;                      // row-within-8 for store reads
    const int scol16 = (l & 7) * 16;              // byte col offset (4 floats)
    f32x16 oacc[2] = {};
    float* attn_base = attn_out + ((size_t)bh*SEQ + q0 + ws*32)*SEQ + kbase;
    stageK(0, 0); stageV(0, 0);
    for (int kt = 0; kt < NT2; ++kt) {
        __syncthreads();
        if (kt < NT2-1) { stageK((kt+1)&1, kt+1); stageV((kt+1)&1, kt+1); }
        const char* kb = (const char*)(kbuf + ((kt&1)*2 + hh)*KB*DH);
        const char* vb = (const char*)(vbuf + ((kt&1)*2 + hh)*KB*DH);
#pragma unroll
        for (int sub = 0; sub < 2; ++sub) {
            f32x16 s = {};
#pragma unroll
            for (int ks = 0; ks < 4; ++ks) {
                int key = sub*32 + q32;
                bf16x8 kf = *(const bf16x8*)(kb + key*128 + ((ks*32 + hi*16) ^ ((key&7)<<4)));
                s = __builtin_amdgcn_mfma_f32_32x32x16_bf16(kf, qf[ks], s, 0, 0, 0);
            }
            float4v pf[4];
#pragma unroll
            for (int rq = 0; rq < 4; ++rq) {
                float4v m4 = *(const float4v*)(mrow + kt*KB + sub*32 + rq*8 + hi*4);
#pragma unroll
                for (int r = 0; r < 4; ++r)
                    pf[rq][r] = __expf(s[rq*4 + r] + (1.0f - m4[r]) * (-1e9f)) * rinv;
            }
            // PV via cvt_pk + permlane32_swap (register path)
#pragma unroll
            for (int half = 0; half < 2; ++half) {
                unsigned int w0 = cvt_pk_bf16(pf[half*2][0], pf[half*2][1]);
                unsigned int w1 = cvt_pk_bf16(pf[half*2][2], pf[half*2][3]);
                unsigned int w2 = cvt_pk_bf16(pf[half*2+1][0], pf[half*2+1][1]);
                unsigned int w3 = cvt_pk_bf16(pf[half*2+1][2], pf[half*2+1][3]);
                asm volatile("v_permlane32_swap_b32 %0, %1" : "+v"(w0), "+v"(w2));
                asm volatile("v_permlane32_swap_b32 %0, %1" : "+v"(w1), "+v"(w3));
                union { unsigned int uu[4]; bf16x8 v; } pa;
                pa.uu[0] = w0; pa.uu[1] = w1; pa.uu[2] = w2; pa.uu[3] = w3;
                const int ks4 = sub*2 + half;
#pragma unroll
                for (int dsub = 0; dsub < 2; ++dsub) {
                    int d = dsub*32 + q32;
                    bf16x8 vf = *(const bf16x8*)(vb + d*128 + ((ks4*32 + hi*16) ^ ((d&7)<<4)));
                    oacc[dsub] = __builtin_amdgcn_mfma_f32_32x32x16_bf16(pa.v, vf, oacc[dsub], 0, 0, 0);
                }
            }
            // coalesced attn store: fenced wave-local transpose through pbuf
#pragma unroll
            for (int c = 0; c < 2; ++c) {
                if ((q32 >> 4) == c) {
                    int row16 = q32 & 15;
#pragma unroll
                    for (int rq = 0; rq < 4; ++rq) {
                        int off = row16*128 + ((rq*32 + hi*16) ^ ((row16 & 7) << 4));
                        *(float4v*)(pw + off) = pf[rq];
                    }
                }
                lds_fence();   // cross-lane write -> read handoff
#pragma unroll
                for (int i = 0; i < 2; ++i) {
                    int row16r = i*8 + srow;
                    int off = row16r*128 + (scol16 ^ ((row16r & 7) << 4));
                    float4v val = *(const float4v*)(pw + off);
                    *(float4v*)(attn_base + (size_t)(c*16 + row16r)*SEQ
                                + kt*KB + sub*32 + (l & 7)*4) = val;
                }
                lds_fence();   // reads complete before next chunk overwrites (WAR)
            }
        }
    }

    // combine ctx partials across key-half wave pairs (stride 36 dodges bank conflicts)
    float* cbuf = (float*)smem;
    __syncthreads();
    if (w >= 4) {
        int base = ((w - 4)*64 + l) * 36;
        *(f32x16*)(cbuf + base) = oacc[0];
        *(f32x16*)(cbuf + base + 16) = oacc[1];
    }
    __syncthreads();
    if (w < 4) {
        int base = (w*64 + l) * 36;
        oacc[0] += *(const f32x16*)(cbuf + base);
        oacc[1] += *(const f32x16*)(cbuf + base + 16);
#pragma unroll
        for (int dsub = 0; dsub < 2; ++dsub) {
            int d = h*DH + dsub*32 + q32;
#pragma unroll
            for (int reg = 0; reg < 16; ++reg) {
                int qr = q0 + ws*32 + (reg&3) + 8*(reg>>2) + 4*hi;
                ctx[(size_t)(b*SEQ + qr)*DM + d] = f2bf(oacc[dsub][reg]);
            }
        }
    }
}

extern "C" void kernel_launch(void* const* d_in, const int* in_sizes, int n_in,
                              void* d_out, int out_size, void* d_ws, size_t ws_size,
                              hipStream_t stream) {
    const float* query = (const float*)d_in[0];
    const float* key_  = (const float*)d_in[1];
    const float* value = (const float*)d_in[2];
    const float* mask  = (const float*)d_in[3];
    const float* W_q = (const float*)d_in[4];
    const float* b_q = (const float*)d_in[5];
    const float* W_k = (const float*)d_in[6];
    const float* b_k = (const float*)d_in[7];
    const float* W_v = (const float*)d_in[8];
    const float* b_v = (const float*)d_in[9];
    const float* W_o = (const float*)d_in[10];
    const float* b_o = (const float*)d_in[11];

    char* ws = (char*)d_ws;
    const size_t SZ = (size_t)MTOT * DM * 2;          // 8 MiB per bf16 [4096][1024]
    unsigned short* xq  = (unsigned short*)(ws);
    unsigned short* xk  = (unsigned short*)(ws + SZ);
    unsigned short* xv  = (unsigned short*)(ws + 2*SZ);
    unsigned short* wtq = (unsigned short*)(ws + 3*SZ);
    unsigned short* wtk = wtq + (size_t)DM*DM;
    unsigned short* wtv = wtk + (size_t)DM*DM;
    unsigned short* wto = wtv + (size_t)DM*DM;
    unsigned short* qws = (unsigned short*)(ws + 4*SZ);
    unsigned short* kws = (unsigned short*)(ws + 5*SZ);
    unsigned short* vtg = (unsigned short*)(ws + 6*SZ);  // per-head V^T from gemm_qkv z=2
    unsigned short* ctx = (unsigned short*)(ws + 7*SZ);
    float* out_f  = (float*)d_out;
    float* attn_f = out_f + (size_t)MTOT * DM;

    prep_kernel<<<dim3(7168), 256, 0, stream>>>(query, key_, value, xq, xk, xv,
                                                W_q, W_k, W_v, W_o, wtq, wtk, wtv, wto);
    gemm_qkv_kernel<<<dim3(16, 32, 3), 256, 0, stream>>>(xq, xk, xv, wtq, wtk, wtv,
                                                         b_q, b_k, b_v, qws, kws, vtg);
    attn_kernel<<<dim3(512), 512, 0, stream>>>(qws, kws, vtg, mask, attn_f, ctx);
    gemm_out_kernel<<<dim3(16, 32), 256, 0, stream>>>(ctx, wto, b_o, out_f);
}

// Round 13
// 261.163 us; speedup vs baseline: 2.6713x; 1.0440x over previous
//
#include <hip/hip_runtime.h>
#include <hip/hip_bf16.h>

#define BATCH 2
#define SEQ 2048
#define DM 1024
#define NH 16
#define DH 64
#define MTOT (BATCH*SEQ)

typedef __attribute__((ext_vector_type(8))) short bf16x8;
typedef __attribute__((ext_vector_type(4))) float f32x4;
typedef __attribute__((ext_vector_type(16))) float f32x16;
typedef __attribute__((ext_vector_type(4))) float float4v;
typedef __attribute__((ext_vector_type(8))) unsigned short u16x8;
typedef __attribute__((ext_vector_type(4))) unsigned short u16x4;

#define GLDS16(g, l) __builtin_amdgcn_global_load_lds(                         \
    (const __attribute__((address_space(1))) void*)(g),                        \
    (__attribute__((address_space(3))) void*)(l), 16, 0, 0)

static __device__ __forceinline__ float bf2f(unsigned short u) {
    unsigned int x = ((unsigned int)u) << 16;
    float f; __builtin_memcpy(&f, &x, 4); return f;
}
static __device__ __forceinline__ unsigned short f2bf(float f) {
    unsigned int x; __builtin_memcpy(&x, &f, 4);
    x += 0x7fffu + ((x >> 16) & 1);   // RNE
    return (unsigned short)(x >> 16);
}
static __device__ __forceinline__ unsigned int cvt_pk_bf16(float a, float b) {
    unsigned int r;
    asm volatile("v_cvt_pk_bf16_f32 %0, %1, %2" : "=v"(r) : "v"(a), "v"(b));
    return r;
}
// RAW handoff fence (R10 bug fix): cross-lane ds_write -> ds_read has no
// compiler dependence edge; drain the LDS queue and pin the schedule.
static __device__ __forceinline__ void lds_fence() {
    __builtin_amdgcn_wave_barrier();
    asm volatile("s_waitcnt lgkmcnt(0)" ::: "memory");
    __builtin_amdgcn_sched_barrier(0);
}
// WAR ordering only: per-wave DS ops execute in order in HW, so a later
// ds_write cannot bypass earlier ds_reads — we only need to stop the
// COMPILER from reordering. No lgkmcnt drain (saves ~120 cyc per use).
static __device__ __forceinline__ void lds_order() {
    __builtin_amdgcn_wave_barrier();
    __builtin_amdgcn_sched_barrier(0);
}

// ---------------- prep: fused {q,k,v fp32->bf16} + {W^T fp32->bf16} ----------------
__global__ __launch_bounds__(256) void prep_kernel(
    const float* __restrict__ q, const float* __restrict__ k, const float* __restrict__ v,
    unsigned short* __restrict__ oq, unsigned short* __restrict__ ok_, unsigned short* __restrict__ ov,
    const float* __restrict__ w0, const float* __restrict__ w1,
    const float* __restrict__ w2, const float* __restrict__ w3,
    unsigned short* __restrict__ t0, unsigned short* __restrict__ t1,
    unsigned short* __restrict__ t2, unsigned short* __restrict__ t3) {
    __shared__ float tile[64][65];
    const int bx = blockIdx.x, t = threadIdx.x;
    if (bx < 6144) {              // cvt part: 3 slabs x 2048 blocks
        const int slab = bx >> 11, bxr = bx & 2047;
        const float* in = slab == 0 ? q : (slab == 1 ? k : v);
        unsigned short* out = slab == 0 ? oq : (slab == 1 ? ok_ : ov);
        size_t i = ((size_t)bxr * 256 + t) * 8;
        float4v a = *(const float4v*)(in + i);
        float4v b = *(const float4v*)(in + i + 4);
        u16x8 r;
        r[0]=f2bf(a[0]); r[1]=f2bf(a[1]); r[2]=f2bf(a[2]); r[3]=f2bf(a[3]);
        r[4]=f2bf(b[0]); r[5]=f2bf(b[1]); r[6]=f2bf(b[2]); r[7]=f2bf(b[3]);
        *(u16x8*)(out + i) = r;
    } else {                      // wtrans part: 4 weights x 256 tiles
        const int i2 = bx - 6144;
        const int z = i2 >> 8, rem = i2 & 255;
        const float* w = z==0 ? w0 : z==1 ? w1 : z==2 ? w2 : w3;
        unsigned short* wt = z==0 ? t0 : z==1 ? t1 : z==2 ? t2 : t3;
        const int k0 = (rem & 15) * 64, n0 = (rem >> 4) * 64;
        const int tr = t >> 4, tc = t & 15;
#pragma unroll
        for (int i = 0; i < 4; ++i) {
            float4v val = *(const float4v*)(w + (size_t)(k0 + tr + 16*i) * DM + n0 + tc*4);
            tile[tr + 16*i][tc*4 + 0] = val[0];
            tile[tr + 16*i][tc*4 + 1] = val[1];
            tile[tr + 16*i][tc*4 + 2] = val[2];
            tile[tr + 16*i][tc*4 + 3] = val[3];
        }
        __syncthreads();
#pragma unroll
        for (int i = 0; i < 4; ++i) {
            u16x4 o;
#pragma unroll
            for (int j = 0; j < 4; ++j) o[j] = f2bf(tile[tc*4 + j][tr + 16*i]);
            *(u16x4*)(wt + (size_t)(n0 + tr + 16*i) * DM + k0 + tc*4) = o;
        }
    }
}

// ---------------- GEMM body: BM=128, BN=64; OUTMODE 0 bf16, 1 f32, 2 per-head-V^T ----------------
template<int OUTMODE>
static __device__ __forceinline__ void gemm_body(
    const unsigned short* __restrict__ A, const unsigned short* __restrict__ Bt,
    const float* __restrict__ bias, void* __restrict__ Cout,
    unsigned short* a_lds, unsigned short* b_lds) {
    constexpr int BM = 128, BN = 64, BK = 64, NT = DM / BK;
    const int tid = threadIdx.x;
    const int m0 = blockIdx.y * BM, n0 = blockIdx.x * BN;
    const int w = tid >> 6, l = tid & 63;
    const int lr = l & 15, lg = l >> 4;
    const int wm = (w >> 1) * 64, wn = (w & 1) * 32;
    f32x4 acc[4][2] = {};

    auto stage = [&](int buf, int kt) {
        const int k0 = kt * BK;
#pragma unroll
        for (int i = 0; i < 4; ++i) {
            int u = i*256 + tid;
            int row = u >> 3, slot = u & 7;
            int sc = (slot ^ (row & 7)) * 8;
            GLDS16(A + (size_t)(m0 + row)*DM + k0 + sc, a_lds + buf*BM*BK + u*8);
        }
#pragma unroll
        for (int i = 0; i < 2; ++i) {
            int u = i*256 + tid;
            int row = u >> 3, slot = u & 7;
            int sc = (slot ^ (row & 7)) * 8;
            GLDS16(Bt + (size_t)(n0 + row)*DM + k0 + sc, b_lds + buf*BN*BK + u*8);
        }
    };

    stage(0, 0);
    for (int kt = 0; kt < NT; ++kt) {
        __syncthreads();
        if (kt < NT-1) stage((kt+1)&1, kt+1);
        const char* ab = (const char*)(a_lds + (kt&1)*BM*BK);
        const char* bb = (const char*)(b_lds + (kt&1)*BN*BK);
        bf16x8 af[4][2], bfr[2][2];
#pragma unroll
        for (int r = 0; r < 4; ++r)
#pragma unroll
            for (int kc = 0; kc < 2; ++kc) {
                int row = wm + r*16 + lr;
                af[r][kc] = *(const bf16x8*)(ab + row*128 + ((kc*64 + lg*16) ^ ((row&7)<<4)));
            }
#pragma unroll
        for (int c = 0; c < 2; ++c)
#pragma unroll
            for (int kc = 0; kc < 2; ++kc) {
                int row = wn + c*16 + lr;
                bfr[c][kc] = *(const bf16x8*)(bb + row*128 + ((kc*64 + lg*16) ^ ((row&7)<<4)));
            }
#pragma unroll
        for (int r = 0; r < 4; ++r)
#pragma unroll
            for (int c = 0; c < 2; ++c)
#pragma unroll
                for (int kc = 0; kc < 2; ++kc)
                    acc[r][c] = __builtin_amdgcn_mfma_f32_16x16x32_bf16(af[r][kc], bfr[c][kc], acc[r][c], 0, 0, 0);
    }

#pragma unroll
    for (int r = 0; r < 4; ++r)
#pragma unroll
        for (int c = 0; c < 2; ++c) {
            int m = m0 + wm + r*16 + lg*4;
            int n = n0 + wn + c*16 + lr;
            float bb = bias[n];
            if constexpr (OUTMODE == 1) {
                float* o = (float*)Cout;
#pragma unroll
                for (int j = 0; j < 4; ++j) o[(size_t)(m+j)*DM + n] = acc[r][c][j] + bb;
            } else if constexpr (OUTMODE == 0) {
                unsigned short* o = (unsigned short*)Cout;
#pragma unroll
                for (int j = 0; j < 4; ++j) o[(size_t)(m+j)*DM + n] = f2bf(acc[r][c][j] + bb);
            } else {
                // per-head V^T: vtg[(b*16 + n/64)*64 + n%64][k], k = m % SEQ (4 contiguous)
                unsigned short* o = (unsigned short*)Cout;
                int bb_ = m >> 11, kk = m & (SEQ-1);
                int bh = bb_ * NH + (n >> 6), d = n & 63;
                u16x4 ov;
#pragma unroll
                for (int j = 0; j < 4; ++j) ov[j] = f2bf(acc[r][c][j] + bb);
                *(u16x4*)(o + ((size_t)bh*DH + d)*SEQ + kk) = ov;
            }
        }
}

__global__ __launch_bounds__(256, 3) void gemm_qkv_kernel(
    const unsigned short* __restrict__ A0, const unsigned short* __restrict__ A1, const unsigned short* __restrict__ A2,
    const unsigned short* __restrict__ B0, const unsigned short* __restrict__ B1, const unsigned short* __restrict__ B2,
    const float* __restrict__ c0, const float* __restrict__ c1, const float* __restrict__ c2,
    unsigned short* __restrict__ O0, unsigned short* __restrict__ O1, unsigned short* __restrict__ O2) {
    __shared__ __align__(16) unsigned short smem[2*128*64 + 2*64*64];   // 48 KB
    const int z = blockIdx.z;
    const unsigned short* A = z==0 ? A0 : z==1 ? A1 : A2;
    const unsigned short* B = z==0 ? B0 : z==1 ? B1 : B2;
    const float* c = z==0 ? c0 : z==1 ? c1 : c2;
    unsigned short* O = z==0 ? O0 : z==1 ? O1 : O2;
    if (z == 2) gemm_body<2>(A, B, c, O, smem, smem + 2*128*64);
    else        gemm_body<0>(A, B, c, O, smem, smem + 2*128*64);
}

__global__ __launch_bounds__(256, 3) void gemm_out_kernel(
    const unsigned short* __restrict__ A, const unsigned short* __restrict__ Bt,
    const float* __restrict__ bias, float* __restrict__ Cout) {
    __shared__ __align__(16) unsigned short smem[2*128*64 + 2*64*64];   // 48 KB
    gemm_body<1>(A, Bt, bias, Cout, smem, smem + 2*128*64);
}

// ---------------- Attention (fused two-pass): KB1=128 den pass + coalesced-store out pass ------
// 8 waves: waves 0-3 q-slabs x keys 0..1023, waves 4-7 same slabs x keys 1024..2047.
// Pass 1 uses the full 64 KB staging space as a KB=128 K double-buffer (8 iters).
// Pass 2: KB=64 K+V double-buffer + fenced wave-local transpose store (R11).
__global__ __launch_bounds__(512, 4) void attn_kernel(
    const unsigned short* __restrict__ qw, const unsigned short* __restrict__ kw,
    const unsigned short* __restrict__ vtg, const float* __restrict__ mask,
    float* __restrict__ attn_out, unsigned short* __restrict__ ctx) {
    constexpr int QB = 128, KB = 64, NT2 = SEQ / KB / 2;     // pass-2: 16 tiles per half
    constexpr int KB1 = 128, NT1 = SEQ / KB1 / 2;            // pass-1: 8 tiles per half
    __shared__ __align__(16) unsigned short smem[4*KB*DH + 4*KB*DH + 8192];  // 80 KB
    unsigned short* kbuf = smem;                  // pass2: [buf][half][64 key][64 k]
    unsigned short* vbuf = smem + 4*KB*DH;        // pass2: [buf][half][64 d][64 key]
    unsigned short* k1   = smem;                  // pass1: [buf][half][128 key][64 k] (64 KB)
    float* pbuf = (float*)(smem + 8*KB*DH);       // [8 waves][16 rows][32 cols] f32, XOR-swizzled
    const int tid = threadIdx.x, w = tid >> 6, l = tid & 63;
    const int hh = w >> 2, ws = w & 3;            // key-half, q-slab
    const int q32 = l & 31, hi = l >> 5;
    const int u0 = (blockIdx.x & 7) * 64 + (blockIdx.x >> 3);  // XCD-chunked
    const int qblk = u0 & 15, bh = u0 >> 4;
    const int b = bh >> 4, h = bh & 15;
    const int q0 = qblk * QB;
    const int q = q0 + ws*32 + q32;
    const int kbase = hh * (SEQ/2);
    char* pw = (char*)(pbuf + w*512);             // this wave's 2 KB transpose buffer

    bf16x8 qf[4];
    {
        const unsigned short* qp = qw + ((size_t)(b*SEQ + q))*DM + h*DH + hi*8;
#pragma unroll
        for (int ks = 0; ks < 4; ++ks) {
            bf16x8 t = *(const bf16x8*)(qp + ks*16);
#pragma unroll
            for (int j = 0; j < 8; ++j) t[j] = (short)f2bf(bf2f((unsigned short)t[j]) * 0.125f);
            qf[ks] = t;
        }
    }

    auto stageK1 = [&](int buf, int kt) {         // 128-key tile per half, 4x GLDS16
#pragma unroll
        for (int hf = 0; hf < 2; ++hf)
#pragma unroll
            for (int i = 0; i < 2; ++i) {
                int u = i*512 + tid;
                int row = u >> 3, slot = u & 7;
                int sc = (slot ^ (row & 7)) * 8;
                const unsigned short* base = kw + ((size_t)(b*SEQ + hf*(SEQ/2) + kt*KB1 + row))*DM + h*DH;
                GLDS16(base + sc, k1 + (buf*2 + hf)*KB1*DH + u*8);
            }
    };
    auto stageK = [&](int buf, int kt) {
#pragma unroll
        for (int hf = 0; hf < 2; ++hf) {
            int row = tid >> 3, slot = tid & 7;
            int sc = (slot ^ (row & 7)) * 8;
            const unsigned short* base = kw + ((size_t)(b*SEQ + hf*(SEQ/2) + kt*KB + row))*DM + h*DH;
            GLDS16(base + sc, kbuf + (buf*2 + hf)*KB*DH + tid*8);
        }
    };
    auto stageV = [&](int buf, int kt) {
#pragma unroll
        for (int hf = 0; hf < 2; ++hf) {
            int row = tid >> 3, slot = tid & 7;           // row = d
            int sc = (slot ^ (row & 7)) * 8;
            const unsigned short* base = vtg + ((size_t)bh*DH + row)*SEQ + hf*(SEQ/2) + kt*KB;
            GLDS16(base + sc, vbuf + (buf*2 + hf)*KB*DH + tid*8);
        }
    };

    const float* mrow = mask + (size_t)b*SEQ + kbase;

    // ---- pass 1: partial softmax denominator (KB1=128, 8 iterations) ----
    float rs = 0.f;
    stageK1(0, 0);
    for (int kt = 0; kt < NT1; ++kt) {
        __syncthreads();
        if (kt < NT1-1) stageK1((kt+1)&1, kt+1);
        const char* kb = (const char*)(k1 + ((kt&1)*2 + hh)*KB1*DH);
#pragma unroll
        for (int sub = 0; sub < 4; ++sub) {
            f32x16 s = {};
#pragma unroll
            for (int ks = 0; ks < 4; ++ks) {
                int key = sub*32 + q32;
                bf16x8 kf = *(const bf16x8*)(kb + key*128 + ((ks*32 + hi*16) ^ ((key&7)<<4)));
                s = __builtin_amdgcn_mfma_f32_32x32x16_bf16(kf, qf[ks], s, 0, 0, 0);
            }
#pragma unroll
            for (int rq = 0; rq < 4; ++rq) {
                float4v m4 = *(const float4v*)(mrow + kt*KB1 + sub*32 + rq*8 + hi*4);
#pragma unroll
                for (int r = 0; r < 4; ++r)
                    rs += __expf(s[rq*4 + r] + (1.0f - m4[r]) * (-1e9f));
            }
        }
    }
    rs += __shfl_xor(rs, 32);
    // combine across key-half wave pairs via LDS (pbuf region)
    {
        float* rbuf = (float*)pbuf;
        __syncthreads();
        rbuf[w*64 + l] = rs;
        __syncthreads();
        rs += rbuf[(w ^ 4)*64 + l];
        __syncthreads();
    }
    const float rinv = 1.0f / rs;

    // ---- pass 2: attn write (coalesced via fenced wave-local transpose) + PV ----
    const int srow = l >> 3;                      // row-within-8 for store reads
    const int scol16 = (l & 7) * 16;              // byte col offset (4 floats)
    f32x16 oacc[2] = {};
    float* attn_base = attn_out + ((size_t)bh*SEQ + q0 + ws*32)*SEQ + kbase;
    stageK(0, 0); stageV(0, 0);
    for (int kt = 0; kt < NT2; ++kt) {
        __syncthreads();
        if (kt < NT2-1) { stageK((kt+1)&1, kt+1); stageV((kt+1)&1, kt+1); }
        const char* kb = (const char*)(kbuf + ((kt&1)*2 + hh)*KB*DH);
        const char* vb = (const char*)(vbuf + ((kt&1)*2 + hh)*KB*DH);
#pragma unroll
        for (int sub = 0; sub < 2; ++sub) {
            f32x16 s = {};
#pragma unroll
            for (int ks = 0; ks < 4; ++ks) {
                int key = sub*32 + q32;
                bf16x8 kf = *(const bf16x8*)(kb + key*128 + ((ks*32 + hi*16) ^ ((key&7)<<4)));
                s = __builtin_amdgcn_mfma_f32_32x32x16_bf16(kf, qf[ks], s, 0, 0, 0);
            }
            float4v pf[4];
#pragma unroll
            for (int rq = 0; rq < 4; ++rq) {
                float4v m4 = *(const float4v*)(mrow + kt*KB + sub*32 + rq*8 + hi*4);
#pragma unroll
                for (int r = 0; r < 4; ++r)
                    pf[rq][r] = __expf(s[rq*4 + r] + (1.0f - m4[r]) * (-1e9f)) * rinv;
            }
            // PV via cvt_pk + permlane32_swap (register path)
#pragma unroll
            for (int half = 0; half < 2; ++half) {
                unsigned int w0 = cvt_pk_bf16(pf[half*2][0], pf[half*2][1]);
                unsigned int w1 = cvt_pk_bf16(pf[half*2][2], pf[half*2][3]);
                unsigned int w2 = cvt_pk_bf16(pf[half*2+1][0], pf[half*2+1][1]);
                unsigned int w3 = cvt_pk_bf16(pf[half*2+1][2], pf[half*2+1][3]);
                asm volatile("v_permlane32_swap_b32 %0, %1" : "+v"(w0), "+v"(w2));
                asm volatile("v_permlane32_swap_b32 %0, %1" : "+v"(w1), "+v"(w3));
                union { unsigned int uu[4]; bf16x8 v; } pa;
                pa.uu[0] = w0; pa.uu[1] = w1; pa.uu[2] = w2; pa.uu[3] = w3;
                const int ks4 = sub*2 + half;
#pragma unroll
                for (int dsub = 0; dsub < 2; ++dsub) {
                    int d = dsub*32 + q32;
                    bf16x8 vf = *(const bf16x8*)(vb + d*128 + ((ks4*32 + hi*16) ^ ((d&7)<<4)));
                    oacc[dsub] = __builtin_amdgcn_mfma_f32_32x32x16_bf16(pa.v, vf, oacc[dsub], 0, 0, 0);
                }
            }
            // coalesced attn store: fenced wave-local transpose through pbuf
#pragma unroll
            for (int c = 0; c < 2; ++c) {
                if ((q32 >> 4) == c) {
                    int row16 = q32 & 15;
#pragma unroll
                    for (int rq = 0; rq < 4; ++rq) {
                        int off = row16*128 + ((rq*32 + hi*16) ^ ((row16 & 7) << 4));
                        *(float4v*)(pw + off) = pf[rq];
                    }
                }
                lds_fence();   // RAW: cross-lane write -> read handoff (needs drain)
#pragma unroll
                for (int i = 0; i < 2; ++i) {
                    int row16r = i*8 + srow;
                    int off = row16r*128 + (scol16 ^ ((row16r & 7) << 4));
                    float4v val = *(const float4v*)(pw + off);
                    *(float4v*)(attn_base + (size_t)(c*16 + row16r)*SEQ
                                + kt*KB + sub*32 + (l & 7)*4) = val;
                }
                lds_order();   // WAR: compiler ordering only (HW DS is in-order per wave)
            }
        }
    }

    // combine ctx partials across key-half wave pairs (stride 36 dodges bank conflicts)
    float* cbuf = (float*)smem;
    __syncthreads();
    if (w >= 4) {
        int base = ((w - 4)*64 + l) * 36;
        *(f32x16*)(cbuf + base) = oacc[0];
        *(f32x16*)(cbuf + base + 16) = oacc[1];
    }
    __syncthreads();
    if (w < 4) {
        int base = (w*64 + l) * 36;
        oacc[0] += *(const f32x16*)(cbuf + base);
        oacc[1] += *(const f32x16*)(cbuf + base + 16);
#pragma unroll
        for (int dsub = 0; dsub < 2; ++dsub) {
            int d = h*DH + dsub*32 + q32;
#pragma unroll
            for (int reg = 0; reg < 16; ++reg) {
                int qr = q0 + ws*32 + (reg&3) + 8*(reg>>2) + 4*hi;
                ctx[(size_t)(b*SEQ + qr)*DM + d] = f2bf(oacc[dsub][reg]);
            }
        }
    }
}

extern "C" void kernel_launch(void* const* d_in, const int* in_sizes, int n_in,
                              void* d_out, int out_size, void* d_ws, size_t ws_size,
                              hipStream_t stream) {
    const float* query = (const float*)d_in[0];
    const float* key_  = (const float*)d_in[1];
    const float* value = (const float*)d_in[2];
    const float* mask  = (const float*)d_in[3];
    const float* W_q = (const float*)d_in[4];
    const float* b_q = (const float*)d_in[5];
    const float* W_k = (const float*)d_in[6];
    const float* b_k = (const float*)d_in[7];
    const float* W_v = (const float*)d_in[8];
    const float* b_v = (const float*)d_in[9];
    const float* W_o = (const float*)d_in[10];
    const float* b_o = (const float*)d_in[11];

    char* ws = (char*)d_ws;
    const size_t SZ = (size_t)MTOT * DM * 2;          // 8 MiB per bf16 [4096][1024]
    unsigned short* xq  = (unsigned short*)(ws);
    unsigned short* xk  = (unsigned short*)(ws + SZ);
    unsigned short* xv  = (unsigned short*)(ws + 2*SZ);
    unsigned short* wtq = (unsigned short*)(ws + 3*SZ);
    unsigned short* wtk = wtq + (size_t)DM*DM;
    unsigned short* wtv = wtk + (size_t)DM*DM;
    unsigned short* wto = wtv + (size_t)DM*DM;
    unsigned short* qws = (unsigned short*)(ws + 4*SZ);
    unsigned short* kws = (unsigned short*)(ws + 5*SZ);
    unsigned short* vtg = (unsigned short*)(ws + 6*SZ);  // per-head V^T from gemm_qkv z=2
    unsigned short* ctx = (unsigned short*)(ws + 7*SZ);
    float* out_f  = (float*)d_out;
    float* attn_f = out_f + (size_t)MTOT * DM;

    prep_kernel<<<dim3(7168), 256, 0, stream>>>(query, key_, value, xq, xk, xv,
                                                W_q, W_k, W_v, W_o, wtq, wtk, wtv, wto);
    gemm_qkv_kernel<<<dim3(16, 32, 3), 256, 0, stream>>>(xq, xk, xv, wtq, wtk, wtv,
                                                         b_q, b_k, b_v, qws, kws, vtg);
    attn_kernel<<<dim3(512), 512, 0, stream>>>(qws, kws, vtg, mask, attn_f, ctx);
    gemm_out_kernel<<<dim3(16, 32), 256, 0, stream>>>(ctx, wto, b_o, out_f);
}

// Round 14
// 252.766 us; speedup vs baseline: 2.7600x; 1.0332x over previous
//
#include <hip/hip_runtime.h>
#include <hip/hip_bf16.h>

#define BATCH 2
#define SEQ 2048
#define DM 1024
#define NH 16
#define DH 64
#define MTOT (BATCH*SEQ)

typedef __attribute__((ext_vector_type(8))) short bf16x8;
typedef __attribute__((ext_vector_type(4))) float f32x4;
typedef __attribute__((ext_vector_type(16))) float f32x16;
typedef __attribute__((ext_vector_type(4))) float float4v;
typedef __attribute__((ext_vector_type(8))) unsigned short u16x8;
typedef __attribute__((ext_vector_type(4))) unsigned short u16x4;

#define GLDS16(g, l) __builtin_amdgcn_global_load_lds(                         \
    (const __attribute__((address_space(1))) void*)(g),                        \
    (__attribute__((address_space(3))) void*)(l), 16, 0, 0)

static __device__ __forceinline__ float bf2f(unsigned short u) {
    unsigned int x = ((unsigned int)u) << 16;
    float f; __builtin_memcpy(&f, &x, 4); return f;
}
static __device__ __forceinline__ unsigned short f2bf(float f) {
    unsigned int x; __builtin_memcpy(&x, &f, 4);
    x += 0x7fffu + ((x >> 16) & 1);   // RNE
    return (unsigned short)(x >> 16);
}
static __device__ __forceinline__ unsigned int cvt_pk_bf16(float a, float b) {
    unsigned int r;
    asm volatile("v_cvt_pk_bf16_f32 %0, %1, %2" : "=v"(r) : "v"(a), "v"(b));
    return r;
}
// RAW handoff fence (R10 bug fix): cross-lane ds_write -> ds_read has no
// compiler dependence edge; drain the LDS queue and pin the schedule.
static __device__ __forceinline__ void lds_fence() {
    __builtin_amdgcn_wave_barrier();
    asm volatile("s_waitcnt lgkmcnt(0)" ::: "memory");
    __builtin_amdgcn_sched_barrier(0);
}
// WAR ordering only: per-wave DS ops execute in order in HW; just stop the
// compiler from reordering (no lgkmcnt drain).
static __device__ __forceinline__ void lds_order() {
    __builtin_amdgcn_wave_barrier();
    __builtin_amdgcn_sched_barrier(0);
}

// ---------------- prep: fused {q,k,v fp32->bf16} + {W^T fp32->bf16} ----------------
__global__ __launch_bounds__(256) void prep_kernel(
    const float* __restrict__ q, const float* __restrict__ k, const float* __restrict__ v,
    unsigned short* __restrict__ oq, unsigned short* __restrict__ ok_, unsigned short* __restrict__ ov,
    const float* __restrict__ w0, const float* __restrict__ w1,
    const float* __restrict__ w2, const float* __restrict__ w3,
    unsigned short* __restrict__ t0, unsigned short* __restrict__ t1,
    unsigned short* __restrict__ t2, unsigned short* __restrict__ t3) {
    __shared__ float tile[64][65];
    const int bx = blockIdx.x, t = threadIdx.x;
    if (bx < 6144) {              // cvt part: 3 slabs x 2048 blocks
        const int slab = bx >> 11, bxr = bx & 2047;
        const float* in = slab == 0 ? q : (slab == 1 ? k : v);
        unsigned short* out = slab == 0 ? oq : (slab == 1 ? ok_ : ov);
        size_t i = ((size_t)bxr * 256 + t) * 8;
        float4v a = *(const float4v*)(in + i);
        float4v b = *(const float4v*)(in + i + 4);
        u16x8 r;
        r[0]=f2bf(a[0]); r[1]=f2bf(a[1]); r[2]=f2bf(a[2]); r[3]=f2bf(a[3]);
        r[4]=f2bf(b[0]); r[5]=f2bf(b[1]); r[6]=f2bf(b[2]); r[7]=f2bf(b[3]);
        *(u16x8*)(out + i) = r;
    } else {                      // wtrans part: 4 weights x 256 tiles
        const int i2 = bx - 6144;
        const int z = i2 >> 8, rem = i2 & 255;
        const float* w = z==0 ? w0 : z==1 ? w1 : z==2 ? w2 : w3;
        unsigned short* wt = z==0 ? t0 : z==1 ? t1 : z==2 ? t2 : t3;
        const int k0 = (rem & 15) * 64, n0 = (rem >> 4) * 64;
        const int tr = t >> 4, tc = t & 15;
#pragma unroll
        for (int i = 0; i < 4; ++i) {
            float4v val = *(const float4v*)(w + (size_t)(k0 + tr + 16*i) * DM + n0 + tc*4);
            tile[tr + 16*i][tc*4 + 0] = val[0];
            tile[tr + 16*i][tc*4 + 1] = val[1];
            tile[tr + 16*i][tc*4 + 2] = val[2];
            tile[tr + 16*i][tc*4 + 3] = val[3];
        }
        __syncthreads();
#pragma unroll
        for (int i = 0; i < 4; ++i) {
            u16x4 o;
#pragma unroll
            for (int j = 0; j < 4; ++j) o[j] = f2bf(tile[tc*4 + j][tr + 16*i]);
            *(u16x4*)(wt + (size_t)(n0 + tr + 16*i) * DM + k0 + tc*4) = o;
        }
    }
}

// ---------------- GEMM body: BM=128, BN=64; OUTMODE 0 bf16, 1 f32, 2 per-head-V^T ----------------
template<int OUTMODE>
static __device__ __forceinline__ void gemm_body(
    const unsigned short* __restrict__ A, const unsigned short* __restrict__ Bt,
    const float* __restrict__ bias, void* __restrict__ Cout,
    unsigned short* a_lds, unsigned short* b_lds) {
    constexpr int BM = 128, BN = 64, BK = 64, NT = DM / BK;
    const int tid = threadIdx.x;
    const int m0 = blockIdx.y * BM, n0 = blockIdx.x * BN;
    const int w = tid >> 6, l = tid & 63;
    const int lr = l & 15, lg = l >> 4;
    const int wm = (w >> 1) * 64, wn = (w & 1) * 32;
    f32x4 acc[4][2] = {};

    auto stage = [&](int buf, int kt) {
        const int k0 = kt * BK;
#pragma unroll
        for (int i = 0; i < 4; ++i) {
            int u = i*256 + tid;
            int row = u >> 3, slot = u & 7;
            int sc = (slot ^ (row & 7)) * 8;
            GLDS16(A + (size_t)(m0 + row)*DM + k0 + sc, a_lds + buf*BM*BK + u*8);
        }
#pragma unroll
        for (int i = 0; i < 2; ++i) {
            int u = i*256 + tid;
            int row = u >> 3, slot = u & 7;
            int sc = (slot ^ (row & 7)) * 8;
            GLDS16(Bt + (size_t)(n0 + row)*DM + k0 + sc, b_lds + buf*BN*BK + u*8);
        }
    };

    stage(0, 0);
    for (int kt = 0; kt < NT; ++kt) {
        __syncthreads();
        if (kt < NT-1) stage((kt+1)&1, kt+1);
        const char* ab = (const char*)(a_lds + (kt&1)*BM*BK);
        const char* bb = (const char*)(b_lds + (kt&1)*BN*BK);
        bf16x8 af[4][2], bfr[2][2];
#pragma unroll
        for (int r = 0; r < 4; ++r)
#pragma unroll
            for (int kc = 0; kc < 2; ++kc) {
                int row = wm + r*16 + lr;
                af[r][kc] = *(const bf16x8*)(ab + row*128 + ((kc*64 + lg*16) ^ ((row&7)<<4)));
            }
#pragma unroll
        for (int c = 0; c < 2; ++c)
#pragma unroll
            for (int kc = 0; kc < 2; ++kc) {
                int row = wn + c*16 + lr;
                bfr[c][kc] = *(const bf16x8*)(bb + row*128 + ((kc*64 + lg*16) ^ ((row&7)<<4)));
            }
#pragma unroll
        for (int r = 0; r < 4; ++r)
#pragma unroll
            for (int c = 0; c < 2; ++c)
#pragma unroll
                for (int kc = 0; kc < 2; ++kc)
                    acc[r][c] = __builtin_amdgcn_mfma_f32_16x16x32_bf16(af[r][kc], bfr[c][kc], acc[r][c], 0, 0, 0);
    }

#pragma unroll
    for (int r = 0; r < 4; ++r)
#pragma unroll
        for (int c = 0; c < 2; ++c) {
            int m = m0 + wm + r*16 + lg*4;
            int n = n0 + wn + c*16 + lr;
            float bb = bias[n];
            if constexpr (OUTMODE == 1) {
                float* o = (float*)Cout;
#pragma unroll
                for (int j = 0; j < 4; ++j) o[(size_t)(m+j)*DM + n] = acc[r][c][j] + bb;
            } else if constexpr (OUTMODE == 0) {
                unsigned short* o = (unsigned short*)Cout;
#pragma unroll
                for (int j = 0; j < 4; ++j) o[(size_t)(m+j)*DM + n] = f2bf(acc[r][c][j] + bb);
            } else {
                // per-head V^T: vtg[(b*16 + n/64)*64 + n%64][k], k = m % SEQ (4 contiguous)
                unsigned short* o = (unsigned short*)Cout;
                int bb_ = m >> 11, kk = m & (SEQ-1);
                int bh = bb_ * NH + (n >> 6), d = n & 63;
                u16x4 ov;
#pragma unroll
                for (int j = 0; j < 4; ++j) ov[j] = f2bf(acc[r][c][j] + bb);
                *(u16x4*)(o + ((size_t)bh*DH + d)*SEQ + kk) = ov;
            }
        }
}

__global__ __launch_bounds__(256, 3) void gemm_qkv_kernel(
    const unsigned short* __restrict__ A0, const unsigned short* __restrict__ A1, const unsigned short* __restrict__ A2,
    const unsigned short* __restrict__ B0, const unsigned short* __restrict__ B1, const unsigned short* __restrict__ B2,
    const float* __restrict__ c0, const float* __restrict__ c1, const float* __restrict__ c2,
    unsigned short* __restrict__ O0, unsigned short* __restrict__ O1, unsigned short* __restrict__ O2) {
    __shared__ __align__(16) unsigned short smem[2*128*64 + 2*64*64];   // 48 KB
    const int z = blockIdx.z;
    const unsigned short* A = z==0 ? A0 : z==1 ? A1 : A2;
    const unsigned short* B = z==0 ? B0 : z==1 ? B1 : B2;
    const float* c = z==0 ? c0 : z==1 ? c1 : c2;
    unsigned short* O = z==0 ? O0 : z==1 ? O1 : O2;
    if (z == 2) gemm_body<2>(A, B, c, O, smem, smem + 2*128*64);
    else        gemm_body<0>(A, B, c, O, smem, smem + 2*128*64);
}

__global__ __launch_bounds__(256, 3) void gemm_out_kernel(
    const unsigned short* __restrict__ A, const unsigned short* __restrict__ Bt,
    const float* __restrict__ bias, float* __restrict__ Cout) {
    __shared__ __align__(16) unsigned short smem[2*128*64 + 2*64*64];   // 48 KB
    gemm_body<1>(A, Bt, bias, Cout, smem, smem + 2*128*64);
}

// ---------------- Attention (fused two-pass): KB1=128 den pass + counted-vmcnt out pass --------
// 8 waves: waves 0-3 q-slabs x keys 0..1023, waves 4-7 same slabs x keys 1024..2047.
// LDS (80 KB exactly, 2 blocks/CU): 64K staging (pass1: KB1=128 K dbuf; pass2: K+V dbuf)
//   + 8K pbuf (8 waves x 1 KB transpose) + 8K madd (pre-folded mask, both passes read via DS).
// Pass-2 barriers use counted vmcnt(8): the 8 attn stores stay in flight across barriers;
// only vmem in the loop is 4 GLDS + 8 stores, so no wait ever forces a store drain.
__global__ __launch_bounds__(512, 4) void attn_kernel(
    const unsigned short* __restrict__ qw, const unsigned short* __restrict__ kw,
    const unsigned short* __restrict__ vtg, const float* __restrict__ mask,
    float* __restrict__ attn_out, unsigned short* __restrict__ ctx) {
    constexpr int QB = 128, KB = 64, NT2 = SEQ / KB / 2;     // pass-2: 16 tiles per half
    constexpr int KB1 = 128, NT1 = SEQ / KB1 / 2;            // pass-1: 8 tiles per half
    __shared__ __align__(16) unsigned short smem[8*KB*DH + 4096 + 4096];  // 64K + 8K + 8K
    unsigned short* kbuf = smem;                  // pass2: [buf][half][64 key][64 k]
    unsigned short* vbuf = smem + 4*KB*DH;        // pass2: [buf][half][64 d][64 key]
    unsigned short* k1   = smem;                  // pass1: [buf][half][128 key][64 k] (64 KB)
    float* pbuf   = (float*)(smem + 8*KB*DH);            // 8 KB: [8 waves][8 rows][32 cols]
    float* madd_f = (float*)(smem + 8*KB*DH + 4096);     // 8 KB: [2048] = (1-mask)*(-1e9)
    const int tid = threadIdx.x, w = tid >> 6, l = tid & 63;
    const int hh = w >> 2, ws = w & 3;            // key-half, q-slab
    const int q32 = l & 31, hi = l >> 5;
    const int u0 = (blockIdx.x & 7) * 64 + (blockIdx.x >> 3);  // XCD-chunked
    const int qblk = u0 & 15, bh = u0 >> 4;
    const int b = bh >> 4, h = bh & 15;
    const int q0 = qblk * QB;
    const int q = q0 + ws*32 + q32;
    const int kbase = hh * (SEQ/2);
    char* pw = (char*)(pbuf + w*256);             // this wave's 1 KB transpose buffer

    // pre-fold mask into LDS once: madd = (1-m)*(-1e9)
    {
        int idx = tid * 4;
        float4v m4 = *(const float4v*)(mask + (size_t)b*SEQ + idx);
        float4v md;
#pragma unroll
        for (int r = 0; r < 4; ++r) md[r] = (1.0f - m4[r]) * (-1e9f);
        *(float4v*)(madd_f + idx) = md;
    }

    bf16x8 qf[4];
    {
        const unsigned short* qp = qw + ((size_t)(b*SEQ + q))*DM + h*DH + hi*8;
#pragma unroll
        for (int ks = 0; ks < 4; ++ks) {
            bf16x8 t = *(const bf16x8*)(qp + ks*16);
#pragma unroll
            for (int j = 0; j < 8; ++j) t[j] = (short)f2bf(bf2f((unsigned short)t[j]) * 0.125f);
            qf[ks] = t;
        }
    }

    auto stageK1 = [&](int buf, int kt) {         // 128-key tile per half, 4x GLDS16
#pragma unroll
        for (int hf = 0; hf < 2; ++hf)
#pragma unroll
            for (int i = 0; i < 2; ++i) {
                int u = i*512 + tid;
                int row = u >> 3, slot = u & 7;
                int sc = (slot ^ (row & 7)) * 8;
                const unsigned short* base = kw + ((size_t)(b*SEQ + hf*(SEQ/2) + kt*KB1 + row))*DM + h*DH;
                GLDS16(base + sc, k1 + (buf*2 + hf)*KB1*DH + u*8);
            }
    };
    auto stageK = [&](int buf, int kt) {
#pragma unroll
        for (int hf = 0; hf < 2; ++hf) {
            int row = tid >> 3, slot = tid & 7;
            int sc = (slot ^ (row & 7)) * 8;
            const unsigned short* base = kw + ((size_t)(b*SEQ + hf*(SEQ/2) + kt*KB + row))*DM + h*DH;
            GLDS16(base + sc, kbuf + (buf*2 + hf)*KB*DH + tid*8);
        }
    };
    auto stageV = [&](int buf, int kt) {
#pragma unroll
        for (int hf = 0; hf < 2; ++hf) {
            int row = tid >> 3, slot = tid & 7;           // row = d
            int sc = (slot ^ (row & 7)) * 8;
            const unsigned short* base = vtg + ((size_t)bh*DH + row)*SEQ + hf*(SEQ/2) + kt*KB;
            GLDS16(base + sc, vbuf + (buf*2 + hf)*KB*DH + tid*8);
        }
    };

    // ---- pass 1: partial softmax denominator (KB1=128, 8 iterations) ----
    float rs = 0.f;
    stageK1(0, 0);
    for (int kt = 0; kt < NT1; ++kt) {
        __syncthreads();
        if (kt < NT1-1) stageK1((kt+1)&1, kt+1);
        const char* kb = (const char*)(k1 + ((kt&1)*2 + hh)*KB1*DH);
#pragma unroll
        for (int sub = 0; sub < 4; ++sub) {
            f32x16 s = {};
#pragma unroll
            for (int ks = 0; ks < 4; ++ks) {
                int key = sub*32 + q32;
                bf16x8 kf = *(const bf16x8*)(kb + key*128 + ((ks*32 + hi*16) ^ ((key&7)<<4)));
                s = __builtin_amdgcn_mfma_f32_32x32x16_bf16(kf, qf[ks], s, 0, 0, 0);
            }
#pragma unroll
            for (int rq = 0; rq < 4; ++rq) {
                float4v m4 = *(const float4v*)(madd_f + kbase + kt*KB1 + sub*32 + rq*8 + hi*4);
#pragma unroll
                for (int r = 0; r < 4; ++r)
                    rs += __expf(s[rq*4 + r] + m4[r]);
            }
        }
    }
    rs += __shfl_xor(rs, 32);
    // combine across key-half wave pairs via LDS (pbuf region)
    {
        float* rbuf = (float*)pbuf;
        __syncthreads();
        rbuf[w*64 + l] = rs;
        __syncthreads();
        rs += rbuf[(w ^ 4)*64 + l];
        __syncthreads();
    }
    const float rinv = 1.0f / rs;

    // ---- pass 2: attn write (coalesced, counted-vmcnt barriers) + PV ----
    const int srow8 = l >> 3;                     // row-within-8 for store reads
    const int scol16 = (l & 7) * 16;              // byte col offset (4 floats)
    f32x16 oacc[2] = {};
    float* attn_base = attn_out + ((size_t)bh*SEQ + q0 + ws*32)*SEQ + kbase;
    stageK(0, 0); stageV(0, 0);
    for (int kt = 0; kt < NT2; ++kt) {
        // Counted barrier: retire only the 4 GLDS of this tile (oldest);
        // the 8 attn stores of the previous tile stay in flight.
        if (kt == 0) asm volatile("s_waitcnt vmcnt(0)" ::: "memory");
        else         asm volatile("s_waitcnt vmcnt(8)" ::: "memory");
        __builtin_amdgcn_s_barrier();
        __builtin_amdgcn_sched_barrier(0);
        if (kt < NT2-1) { stageK((kt+1)&1, kt+1); stageV((kt+1)&1, kt+1); }
        const char* kb = (const char*)(kbuf + ((kt&1)*2 + hh)*KB*DH);
        const char* vb = (const char*)(vbuf + ((kt&1)*2 + hh)*KB*DH);
#pragma unroll
        for (int sub = 0; sub < 2; ++sub) {
            f32x16 s = {};
#pragma unroll
            for (int ks = 0; ks < 4; ++ks) {
                int key = sub*32 + q32;
                bf16x8 kf = *(const bf16x8*)(kb + key*128 + ((ks*32 + hi*16) ^ ((key&7)<<4)));
                s = __builtin_amdgcn_mfma_f32_32x32x16_bf16(kf, qf[ks], s, 0, 0, 0);
            }
            float4v pf[4];
#pragma unroll
            for (int rq = 0; rq < 4; ++rq) {
                float4v m4 = *(const float4v*)(madd_f + kbase + kt*KB + sub*32 + rq*8 + hi*4);
#pragma unroll
                for (int r = 0; r < 4; ++r)
                    pf[rq][r] = __expf(s[rq*4 + r] + m4[r]) * rinv;
            }
            // PV via cvt_pk + permlane32_swap (register path)
#pragma unroll
            for (int half = 0; half < 2; ++half) {
                unsigned int w0 = cvt_pk_bf16(pf[half*2][0], pf[half*2][1]);
                unsigned int w1 = cvt_pk_bf16(pf[half*2][2], pf[half*2][3]);
                unsigned int w2 = cvt_pk_bf16(pf[half*2+1][0], pf[half*2+1][1]);
                unsigned int w3 = cvt_pk_bf16(pf[half*2+1][2], pf[half*2+1][3]);
                asm volatile("v_permlane32_swap_b32 %0, %1" : "+v"(w0), "+v"(w2));
                asm volatile("v_permlane32_swap_b32 %0, %1" : "+v"(w1), "+v"(w3));
                union { unsigned int uu[4]; bf16x8 v; } pa;
                pa.uu[0] = w0; pa.uu[1] = w1; pa.uu[2] = w2; pa.uu[3] = w3;
                const int ks4 = sub*2 + half;
#pragma unroll
                for (int dsub = 0; dsub < 2; ++dsub) {
                    int d = dsub*32 + q32;
                    bf16x8 vf = *(const bf16x8*)(vb + d*128 + ((ks4*32 + hi*16) ^ ((d&7)<<4)));
                    oacc[dsub] = __builtin_amdgcn_mfma_f32_32x32x16_bf16(pa.v, vf, oacc[dsub], 0, 0, 0);
                }
            }
            // coalesced attn store: fenced wave-local transpose, 4 chunks of 8 rows (1 KB pbuf)
#pragma unroll
            for (int c = 0; c < 4; ++c) {
                if ((q32 >> 3) == c) {
                    int row8 = q32 & 7;
#pragma unroll
                    for (int rq = 0; rq < 4; ++rq) {
                        int off = row8*128 + ((rq*32 + hi*16) ^ (row8 << 4));
                        *(float4v*)(pw + off) = pf[rq];
                    }
                }
                lds_fence();   // RAW: cross-lane write -> read handoff (needs drain)
                {
                    int off = srow8*128 + (scol16 ^ (srow8 << 4));
                    float4v val = *(const float4v*)(pw + off);
                    *(float4v*)(attn_base + (size_t)(c*8 + srow8)*SEQ
                                + kt*KB + sub*32 + (l & 7)*4) = val;
                }
                lds_order();   // WAR: compiler ordering only (HW DS is in-order per wave)
            }
        }
    }

    // combine ctx partials across key-half wave pairs (stride 36 dodges bank conflicts)
    float* cbuf = (float*)smem;
    __syncthreads();
    if (w >= 4) {
        int base = ((w - 4)*64 + l) * 36;
        *(f32x16*)(cbuf + base) = oacc[0];
        *(f32x16*)(cbuf + base + 16) = oacc[1];
    }
    __syncthreads();
    if (w < 4) {
        int base = (w*64 + l) * 36;
        oacc[0] += *(const f32x16*)(cbuf + base);
        oacc[1] += *(const f32x16*)(cbuf + base + 16);
#pragma unroll
        for (int dsub = 0; dsub < 2; ++dsub) {
            int d = h*DH + dsub*32 + q32;
#pragma unroll
            for (int reg = 0; reg < 16; ++reg) {
                int qr = q0 + ws*32 + (reg&3) + 8*(reg>>2) + 4*hi;
                ctx[(size_t)(b*SEQ + qr)*DM + d] = f2bf(oacc[dsub][reg]);
            }
        }
    }
}

extern "C" void kernel_launch(void* const* d_in, const int* in_sizes, int n_in,
                              void* d_out, int out_size, void* d_ws, size_t ws_size,
                              hipStream_t stream) {
    const float* query = (const float*)d_in[0];
    const float* key_  = (const float*)d_in[1];
    const float* value = (const float*)d_in[2];
    const float* mask  = (const float*)d_in[3];
    const float* W_q = (const float*)d_in[4];
    const float* b_q = (const float*)d_in[5];
    const float* W_k = (const float*)d_in[6];
    const float* b_k = (const float*)d_in[7];
    const float* W_v = (const float*)d_in[8];
    const float* b_v = (const float*)d_in[9];
    const float* W_o = (const float*)d_in[10];
    const float* b_o = (const float*)d_in[11];

    char* ws = (char*)d_ws;
    const size_t SZ = (size_t)MTOT * DM * 2;          // 8 MiB per bf16 [4096][1024]
    unsigned short* xq  = (unsigned short*)(ws);
    unsigned short* xk  = (unsigned short*)(ws + SZ);
    unsigned short* xv  = (unsigned short*)(ws + 2*SZ);
    unsigned short* wtq = (unsigned short*)(ws + 3*SZ);
    unsigned short* wtk = wtq + (size_t)DM*DM;
    unsigned short* wtv = wtk + (size_t)DM*DM;
    unsigned short* wto = wtv + (size_t)DM*DM;
    unsigned short* qws = (unsigned short*)(ws + 4*SZ);
    unsigned short* kws = (unsigned short*)(ws + 5*SZ);
    unsigned short* vtg = (unsigned short*)(ws + 6*SZ);  // per-head V^T from gemm_qkv z=2
    unsigned short* ctx = (unsigned short*)(ws + 7*SZ);
    float* out_f  = (float*)d_out;
    float* attn_f = out_f + (size_t)MTOT * DM;

    prep_kernel<<<dim3(7168), 256, 0, stream>>>(query, key_, value, xq, xk, xv,
                                                W_q, W_k, W_v, W_o, wtq, wtk, wtv, wto);
    gemm_qkv_kernel<<<dim3(16, 32, 3), 256, 0, stream>>>(xq, xk, xv, wtq, wtk, wtv,
                                                         b_q, b_k, b_v, qws, kws, vtg);
    attn_kernel<<<dim3(512), 512, 0, stream>>>(qws, kws, vtg, mask, attn_f, ctx);
    gemm_out_kernel<<<dim3(16, 32), 256, 0, stream>>>(ctx, wto, b_o, out_f);
}